// Round 12
// baseline (3218.279 us; speedup 1.0000x reference)
//
#include <hip/hip_runtime.h>
#include <math.h>

typedef unsigned short ushort_t;
typedef short bf16x8 __attribute__((ext_vector_type(8)));   // 8 bf16 = 4 VGPRs (MFMA A/B frag)
typedef float f32x4 __attribute__((ext_vector_type(4)));    // MFMA C/D frag

#define BN_ 4096
#define SN 24
#define TN 24
#define EN 128
#define HN 512
#define GN 1536
#define VN 256
#define BOW_ 1

// Persistent-row design: blocks own rows for the ENTIRE sequence.
//  - h state in LDS as bf16 hi(cols 0..511)/lo(512..1023), XOR-swizzled:
//    elem(row,col) at [row][((col>>3)^(row&7))*8 + (col&7)]  -> A-frag ds_read_b128
//    touches all 32 banks 2-way (free); epilogue writes are per-lane scalar.
//  - Recurrent GEMM: 2-term split (exact-h x bf16(U)): per kc (BK=32, K=512):
//    acc += Ahi[kc] x U[kc] ; acc += Alo[kc] x U[kc]  (B loaded once).
//  - Logits: 3-term (Ahi+Alo) x Wohi + Ahi x Wolo.
//  - B operands stream global->VGPR (16B/lane frags = whole 64B lines), L2-resident.
#define SWZ(row, col) ((((col) >> 3) ^ ((row) & 7)) * 8 + ((col) & 7))

__device__ __forceinline__ float bf2f(ushort_t u) {
    union { unsigned int i; float f; } v; v.i = ((unsigned int)u) << 16; return v.f;
}
__device__ __forceinline__ ushort_t f2bf(float f) {  // round-to-nearest-even
    union { float f; unsigned int i; } v; v.f = f;
    unsigned int r = (v.i + 0x7FFFu + ((v.i >> 16) & 1u)) >> 16;
    return (ushort_t)r;
}

// ===== P = emb @ W + b_input, tiled (64x64 tiles, K=128 staged in LDS) =====
__global__ __launch_bounds__(256) void precomp_P(
    const float* __restrict__ src_emb, const float* __restrict__ tgt_emb,
    const float* __restrict__ Wf, const float* __restrict__ bf,
    const float* __restrict__ Wb, const float* __restrict__ bb,
    const float* __restrict__ Wd, const float* __restrict__ bd,
    float* __restrict__ Pf, float* __restrict__ Pb, float* __restrict__ Pd) {
    const int mat = blockIdx.z;
    const float* emb = (mat == 2) ? tgt_emb : src_emb;
    const float* W   = (mat == 0) ? Wf : (mat == 1) ? Wb : Wd;
    const float* bia = (mat == 0) ? bf : (mat == 1) ? bb : bd;
    float* P         = (mat == 0) ? Pf : (mat == 1) ? Pb : Pd;

    const int bm = blockIdx.x * 64;
    const int bn = blockIdx.y * 64;
    const int tid = threadIdx.x;
    const int tx = tid & 15;
    const int ty = tid >> 4;

    __shared__ __align__(16) float As[64][17];
    __shared__ __align__(16) float Bs[16][64];

    float acc[4][4];
#pragma unroll
    for (int i = 0; i < 4; i++)
#pragma unroll
        for (int j = 0; j < 4; j++) acc[i][j] = 0.0f;

    const int ar = tid >> 2;
    const int ak = (tid & 3) * 4;
    const int bk = tid >> 4;
    const int bc = (tid & 15) * 4;

    for (int k0 = 0; k0 < EN; k0 += 16) {
        float4 av = *reinterpret_cast<const float4*>(&emb[(bm + ar) * EN + k0 + ak]);
        As[ar][ak + 0] = av.x; As[ar][ak + 1] = av.y; As[ar][ak + 2] = av.z; As[ar][ak + 3] = av.w;
        float4 bv = *reinterpret_cast<const float4*>(&W[(k0 + bk) * GN + bn + bc]);
        *reinterpret_cast<float4*>(&Bs[bk][bc]) = bv;
        __syncthreads();
#pragma unroll
        for (int kk = 0; kk < 16; kk++) {
            float a[4];
#pragma unroll
            for (int i = 0; i < 4; i++) a[i] = As[ty * 4 + i][kk];
            float4 b4 = *reinterpret_cast<float4*>(&Bs[kk][tx * 4]);
#pragma unroll
            for (int i = 0; i < 4; i++) {
                acc[i][0] += a[i] * b4.x;
                acc[i][1] += a[i] * b4.y;
                acc[i][2] += a[i] * b4.z;
                acc[i][3] += a[i] * b4.w;
            }
        }
        __syncthreads();
    }

#pragma unroll
    for (int i = 0; i < 4; i++) {
        const int row = bm + ty * 4 + i;
#pragma unroll
        for (int j = 0; j < 4; j++) {
            const int col = bn + tx * 4 + j;
            P[(size_t)row * GN + col] = acc[i][j] + bia[col];
        }
    }
}

// ===== Bt[col][k] = bf16(U[k][col]) via LDS tile transpose. grid (24, 8, 3). =====
__global__ __launch_bounds__(256) void transpose_Bt(
    const float* __restrict__ Uf, const float* __restrict__ Ub, const float* __restrict__ Ud,
    ushort_t* __restrict__ BtF, ushort_t* __restrict__ BtB, ushort_t* __restrict__ BtD) {
    const int mat = blockIdx.z;
    const float* U = (mat == 0) ? Uf : (mat == 1) ? Ub : Ud;
    ushort_t* Bt   = (mat == 0) ? BtF : (mat == 1) ? BtB : BtD;
    const int ct = blockIdx.x * 64;
    const int kt = blockIdx.y * 64;
    const int tid = threadIdx.x;
    __shared__ float tile[64][65];
#pragma unroll
    for (int rr = 0; rr < 64; rr += 4) {
        const int r = rr + (tid >> 6);
        const int c = tid & 63;
        tile[r][c] = U[(size_t)(kt + r) * GN + ct + c];
    }
    __syncthreads();
#pragma unroll
    for (int cc = 0; cc < 64; cc += 4) {
        const int c = cc + (tid >> 6);
        const int k = tid & 63;
        Bt[(size_t)(ct + c) * HN + kt + k] = f2bf(tile[k][c]);
    }
}

// ===== Wot[col][k]=hi, [col][512+k]=lo of Wo[k][col]. grid (4, 8). =====
__global__ __launch_bounds__(256) void transpose_Wot(
    const float* __restrict__ Wo, ushort_t* __restrict__ Wot) {
    const int ct = blockIdx.x * 64;
    const int kt = blockIdx.y * 64;
    const int tid = threadIdx.x;
    __shared__ float tile[64][65];
#pragma unroll
    for (int rr = 0; rr < 64; rr += 4) {
        const int r = rr + (tid >> 6);
        const int c = tid & 63;
        tile[r][c] = Wo[(size_t)(kt + r) * VN + ct + c];
    }
    __syncthreads();
#pragma unroll
    for (int cc = 0; cc < 64; cc += 4) {
        const int c = cc + (tid >> 6);
        const int k = tid & 63;
        float u = tile[k][c];
        ushort_t hi = f2bf(u);
        Wot[(size_t)(ct + c) * 1024 + kt + k] = hi;
        Wot[(size_t)(ct + c) * 1024 + 512 + kt + k] = f2bf(u - bf2f(hi));
    }
}

// ===== Persistent encoder: 256 blocks x 512 threads; block = 32 rows, all 24 steps. =====
// XCD = bx&7: 0-3 fwd, 4-7 bwd (B slice L2-pinned per XCD). 8 waves: wave w = 32 rows x
// 64 h-cols (c0 = w*64) x 3 gates. LDS padded to 96 KB -> exactly 1 block/CU.
__global__ __launch_bounds__(512, 2) void enc_persist(
    const ushort_t* __restrict__ BtF, const ushort_t* __restrict__ BtB,
    const float* __restrict__ Pf, const float* __restrict__ Pb,
    const float* __restrict__ brF, const float* __restrict__ brB,
    const int* __restrict__ src,
    ushort_t* __restrict__ hfFin, ushort_t* __restrict__ hbFin) {
    const int bx = blockIdx.x;
    const int rev = ((bx & 7) >= 4);
    const int rtile = (bx >> 3) * 4 + (bx & 3);   // 0..127 within dir
    const int r0 = rtile * 32;
    const ushort_t* Bt = rev ? BtB : BtF;
    const float* P     = rev ? Pb : Pf;
    const float* brec  = rev ? brB : brF;
    ushort_t* fin      = rev ? hbFin : hfFin;

    const int tid = threadIdx.x;
    const int lane = tid & 63;
    const int w = tid >> 6;
    const int c0 = w * 64;
    const int fl = lane & 15;
    const int k8 = lane >> 4;     // 0..3

    __shared__ ushort_t state[48][1024];   // rows 0..31 used; 96 KB forces 1 block/CU

    for (int i = tid; i < 32 * 1024; i += 512) ((ushort_t*)state)[i] = 0;

    float hreg[2][4][4];   // [m][f][q]: row = m*16 + k8*4 + q, col = c0 + f*16 + fl
#pragma unroll
    for (int m = 0; m < 2; m++)
#pragma unroll
        for (int f = 0; f < 4; f++)
#pragma unroll
            for (int q = 0; q < 4; q++) hreg[m][f][q] = 0.f;

    float brz[4], brr[4], brh[4];
#pragma unroll
    for (int f = 0; f < 4; f++) {
        const int col = c0 + f * 16 + fl;
        brz[f] = brec[col]; brr[f] = brec[HN + col]; brh[f] = brec[2 * HN + col];
    }
    __syncthreads();

    for (int t = 0; t < SN; ++t) {
        f32x4 acc[3][4][2];
#pragma unroll
        for (int g = 0; g < 3; g++)
#pragma unroll
            for (int f = 0; f < 4; f++)
#pragma unroll
                for (int m = 0; m < 2; m++) acc[g][f][m] = (f32x4){0.f, 0.f, 0.f, 0.f};

#pragma unroll 1
        for (int kc = 0; kc < 16; ++kc) {
            bf16x8 ah[2], al[2];
#pragma unroll
            for (int m = 0; m < 2; m++) {
                const int row = m * 16 + fl;
                ah[m] = *(const bf16x8*)&state[row][((kc * 4 + k8) ^ (row & 7)) * 8];
                al[m] = *(const bf16x8*)&state[row][((64 + kc * 4 + k8) ^ (row & 7)) * 8];
            }
            bf16x8 b[3][4];
#pragma unroll
            for (int g = 0; g < 3; g++)
#pragma unroll
                for (int f = 0; f < 4; f++)
                    b[g][f] = *(const bf16x8*)&Bt[(size_t)(g * HN + c0 + f * 16 + fl) * HN + kc * 32 + k8 * 8];
#pragma unroll
            for (int g = 0; g < 3; g++)
#pragma unroll
                for (int f = 0; f < 4; f++)
#pragma unroll
                    for (int m = 0; m < 2; m++) {
                        acc[g][f][m] = __builtin_amdgcn_mfma_f32_16x16x32_bf16(ah[m], b[g][f], acc[g][f][m], 0, 0, 0);
                        acc[g][f][m] = __builtin_amdgcn_mfma_f32_16x16x32_bf16(al[m], b[g][f], acc[g][f][m], 0, 0, 0);
                    }
        }
        __syncthreads();   // all waves done reading state for step t

#pragma unroll
        for (int m = 0; m < 2; m++)
#pragma unroll
            for (int q = 0; q < 4; q++) {
                const int row = m * 16 + k8 * 4 + q;
                const int grow = r0 + row;
                const int idx = src[grow * SN + (rev ? (SN - 1 - t) : t)];
                const float* Pr = P + (size_t)idx * GN;
#pragma unroll
                for (int f = 0; f < 4; f++) {
                    const int col = c0 + f * 16 + fl;
                    float rz = acc[0][f][m][q] + brz[f];
                    float rr_ = acc[1][f][m][q] + brr[f];
                    float rh = acc[2][f][m][q] + brh[f];
                    float z = 1.f / (1.f + expf(-(Pr[col] + rz)));
                    float r = 1.f / (1.f + expf(-(Pr[HN + col] + rr_)));
                    float hh = tanhf(Pr[2 * HN + col] + r * rh);
                    float hnew = z * hreg[m][f][q] + (1.f - z) * hh;
                    ushort_t hib = f2bf(hnew);
                    ushort_t lob = f2bf(hnew - bf2f(hib));
                    hreg[m][f][q] = bf2f(hib) + bf2f(lob);
                    state[row][SWZ(row, col)] = hib;
                    state[row][SWZ(row, HN + col)] = lob;
                }
            }
        __syncthreads();   // writes visible before next step's reads
    }

    for (int i = tid; i < 32 * 1024; i += 512) {
        const int row = i >> 10, col = i & 1023;
        fin[(size_t)(r0 + row) * 1024 + col] = state[row][SWZ(row, col)];
    }
}

// ===== Persistent decoder + fused logits: 256 blocks x 512 threads; block = 16 rows. =====
__global__ __launch_bounds__(512, 2) void dec_persist(
    const ushort_t* __restrict__ BtD, const float* __restrict__ Pd,
    const float* __restrict__ brD, const int* __restrict__ tgt,
    const ushort_t* __restrict__ Wot, const float* __restrict__ bo,
    const ushort_t* __restrict__ hfFin, const ushort_t* __restrict__ hbFin,
    float* __restrict__ out) {
    const int bx = blockIdx.x;
    const int r0 = bx * 16;
    const int tid = threadIdx.x;
    const int lane = tid & 63;
    const int w = tid >> 6;
    const int c0 = w * 64;
    const int v0 = w * 32;
    const int fl = lane & 15;
    const int k8 = lane >> 4;

    __shared__ ushort_t state[48][1024];   // rows 0..15 used; 96 KB forces 1 block/CU

    // init state = hf_final + hb_final (hi/lo re-split)
    for (int i = tid; i < 16 * HN; i += 512) {
        const int row = i >> 9, col = i & (HN - 1);
        const int grow = r0 + row;
        float h = bf2f(hfFin[(size_t)grow * 1024 + col]) + bf2f(hfFin[(size_t)grow * 1024 + HN + col])
                + bf2f(hbFin[(size_t)grow * 1024 + col]) + bf2f(hbFin[(size_t)grow * 1024 + HN + col]);
        ushort_t hib = f2bf(h);
        state[row][SWZ(row, col)] = hib;
        state[row][SWZ(row, HN + col)] = f2bf(h - bf2f(hib));
    }

    float hreg[4][4];   // [f][q]: row = k8*4 + q, col = c0 + f*16 + fl
#pragma unroll
    for (int f = 0; f < 4; f++)
#pragma unroll
        for (int q = 0; q < 4; q++) {
            const int row = k8 * 4 + q;
            const int col = c0 + f * 16 + fl;
            const int grow = r0 + row;
            float h = bf2f(hfFin[(size_t)grow * 1024 + col]) + bf2f(hfFin[(size_t)grow * 1024 + HN + col])
                    + bf2f(hbFin[(size_t)grow * 1024 + col]) + bf2f(hbFin[(size_t)grow * 1024 + HN + col]);
            ushort_t hib = f2bf(h);
            ushort_t lob = f2bf(h - bf2f(hib));
            hreg[f][q] = bf2f(hib) + bf2f(lob);
        }

    float brz[4], brr[4], brh[4];
#pragma unroll
    for (int f = 0; f < 4; f++) {
        const int col = c0 + f * 16 + fl;
        brz[f] = brD[col]; brr[f] = brD[HN + col]; brh[f] = brD[2 * HN + col];
    }
    float boL[2];
#pragma unroll
    for (int fv = 0; fv < 2; fv++) boL[fv] = bo[v0 + fv * 16 + fl];
    __syncthreads();

    for (int t = 0; t < TN; ++t) {
        // ---- recurrence GEMM ----
        f32x4 acc[3][4];
#pragma unroll
        for (int g = 0; g < 3; g++)
#pragma unroll
            for (int f = 0; f < 4; f++) acc[g][f] = (f32x4){0.f, 0.f, 0.f, 0.f};

#pragma unroll 1
        for (int kc = 0; kc < 16; ++kc) {
            const int row = fl;
            bf16x8 ah = *(const bf16x8*)&state[row][((kc * 4 + k8) ^ (row & 7)) * 8];
            bf16x8 al = *(const bf16x8*)&state[row][((64 + kc * 4 + k8) ^ (row & 7)) * 8];
            bf16x8 b[3][4];
#pragma unroll
            for (int g = 0; g < 3; g++)
#pragma unroll
                for (int f = 0; f < 4; f++)
                    b[g][f] = *(const bf16x8*)&BtD[(size_t)(g * HN + c0 + f * 16 + fl) * HN + kc * 32 + k8 * 8];
#pragma unroll
            for (int g = 0; g < 3; g++)
#pragma unroll
                for (int f = 0; f < 4; f++) {
                    acc[g][f] = __builtin_amdgcn_mfma_f32_16x16x32_bf16(ah, b[g][f], acc[g][f], 0, 0, 0);
                    acc[g][f] = __builtin_amdgcn_mfma_f32_16x16x32_bf16(al, b[g][f], acc[g][f], 0, 0, 0);
                }
        }
        __syncthreads();

        // ---- gate epilogue ----
#pragma unroll
        for (int q = 0; q < 4; q++) {
            const int row = k8 * 4 + q;
            const int grow = r0 + row;
            const int idx = (t == 0) ? BOW_ : tgt[grow * TN + (t - 1)];
            const float* Pr = Pd + (size_t)idx * GN;
#pragma unroll
            for (int f = 0; f < 4; f++) {
                const int col = c0 + f * 16 + fl;
                float rz = acc[0][f][q] + brz[f];
                float rr_ = acc[1][f][q] + brr[f];
                float rh = acc[2][f][q] + brh[f];
                float z = 1.f / (1.f + expf(-(Pr[col] + rz)));
                float r = 1.f / (1.f + expf(-(Pr[HN + col] + rr_)));
                float hh = tanhf(Pr[2 * HN + col] + r * rh);
                float hnew = z * hreg[f][q] + (1.f - z) * hh;
                ushort_t hib = f2bf(hnew);
                ushort_t lob = f2bf(hnew - bf2f(hib));
                hreg[f][q] = bf2f(hib) + bf2f(lob);
                state[row][SWZ(row, col)] = hib;
                state[row][SWZ(row, HN + col)] = lob;
            }
        }
        __syncthreads();

        // ---- logits (3-term) on updated state ----
        f32x4 accL[2];
#pragma unroll
        for (int fv = 0; fv < 2; fv++) accL[fv] = (f32x4){0.f, 0.f, 0.f, 0.f};

#pragma unroll 1
        for (int kc = 0; kc < 16; ++kc) {
            const int row = fl;
            bf16x8 ah = *(const bf16x8*)&state[row][((kc * 4 + k8) ^ (row & 7)) * 8];
            bf16x8 al = *(const bf16x8*)&state[row][((64 + kc * 4 + k8) ^ (row & 7)) * 8];
#pragma unroll
            for (int fv = 0; fv < 2; fv++) {
                const size_t wbase = (size_t)(v0 + fv * 16 + fl) * 1024 + kc * 32 + k8 * 8;
                bf16x8 wh = *(const bf16x8*)&Wot[wbase];
                bf16x8 wl = *(const bf16x8*)&Wot[wbase + HN];
                accL[fv] = __builtin_amdgcn_mfma_f32_16x16x32_bf16(ah, wh, accL[fv], 0, 0, 0);
                accL[fv] = __builtin_amdgcn_mfma_f32_16x16x32_bf16(al, wh, accL[fv], 0, 0, 0);
                accL[fv] = __builtin_amdgcn_mfma_f32_16x16x32_bf16(ah, wl, accL[fv], 0, 0, 0);
            }
        }
#pragma unroll
        for (int fv = 0; fv < 2; fv++)
#pragma unroll
            for (int q = 0; q < 4; q++) {
                const int row = k8 * 4 + q;
                const int col = v0 + fv * 16 + fl;
                out[(size_t)(r0 + row) * (TN * VN) + t * VN + col] = accL[fv][q] + boL[fv];
            }
        // no barrier needed: next iteration's first barrier orders logits reads
        // against the next epilogue's state writes.
    }
}

extern "C" void kernel_launch(void* const* d_in, const int* in_sizes, int n_in,
                              void* d_out, int out_size, void* d_ws, size_t ws_size,
                              hipStream_t stream) {
    const int* source    = (const int*)d_in[0];
    const int* targets   = (const int*)d_in[1];
    const float* src_emb = (const float*)d_in[2];
    const float* tgt_emb = (const float*)d_in[3];
    const float* Wf = (const float*)d_in[4];
    const float* Uf = (const float*)d_in[5];
    const float* bf = (const float*)d_in[6];
    const float* Wb = (const float*)d_in[7];
    const float* Ub = (const float*)d_in[8];
    const float* bb = (const float*)d_in[9];
    const float* Wd = (const float*)d_in[10];
    const float* Ud = (const float*)d_in[11];
    const float* bd = (const float*)d_in[12];
    const float* Wo = (const float*)d_in[13];
    const float* bo = (const float*)d_in[14];
    float* out = (float*)d_out;

    char* ws = (char*)d_ws;
    ushort_t* BtF = (ushort_t*)(ws);                         // 1536*512*2 = 1572864 each
    ushort_t* BtB = (ushort_t*)(ws + 1572864);
    ushort_t* BtD = (ushort_t*)(ws + 2 * 1572864);
    ushort_t* Wot = (ushort_t*)(ws + 3 * 1572864);           // 256*1024*2 = 524288
    float*    Pf  = (float*)   (ws + 3 * 1572864 + 524288);  // 3 x 256*1536*4
    float*    Pb  = Pf + VN * GN;
    float*    Pd  = Pb + VN * GN;
    ushort_t* hfFin = (ushort_t*)(ws + 3 * 1572864 + 524288 + 4718592);   // 4096*1024*2 = 8388608
    ushort_t* hbFin = (ushort_t*)(ws + 3 * 1572864 + 524288 + 4718592 + 8388608);

    precomp_P<<<dim3(4, 24, 3), 256, 0, stream>>>(src_emb, tgt_emb, Wf, bf, Wb, bb, Wd, bd, Pf, Pb, Pd);
    transpose_Bt<<<dim3(24, 8, 3), 256, 0, stream>>>(Uf, Ub, Ud, BtF, BtB, BtD);
    transpose_Wot<<<dim3(4, 8), 256, 0, stream>>>(Wo, Wot);

    enc_persist<<<256, 512, 0, stream>>>(BtF, BtB, Pf, Pb, bf + GN, bb + GN, source, hfFin, hbFin);
    dec_persist<<<256, 512, 0, stream>>>(BtD, Pd, bd + GN, targets, Wot, bo, hfFin, hbFin, out);
}

// Round 14
// 1997.424 us; speedup vs baseline: 1.6112x; 1.6112x over previous
//
#include <hip/hip_runtime.h>
#include <math.h>

typedef unsigned short ushort_t;
typedef short bf16x8 __attribute__((ext_vector_type(8)));   // 8 bf16 = 4 VGPRs (MFMA A/B frag)
typedef float f32x4 __attribute__((ext_vector_type(4)));    // MFMA C/D frag

#define BN_ 4096
#define SN 24
#define TN 24
#define EN 128
#define HN 512
#define GN 1536
#define VN 256
#define BOW_ 1
#define HC 1024   // hcat row stride: [hi(512) | lo(512)]
// Recurrent GEMMs: 2-term split, 16 chunks of BK=32, B STAGED ONCE per chunk:
//   per kc: stage {A-hi(k=kc*32), A-lo(k=512+kc*32), B chunk kc}; acc += Ahi x B + Alo x B.
// Logits: 3-term split, 48 chunks of BK=32:
//   kc 0..15  : Ahi(k=kc*32)        x Wohi chunk kc
//   kc 16..31 : Alo(k=512+(kc-16)*32) x Wohi chunk kc-16
//   kc 32..47 : Ahi(k=(kc-32)*32)   x Wolo chunk 16+(kc-32)

__device__ __forceinline__ float bf2f(ushort_t u) {
    union { unsigned int i; float f; } v; v.i = ((unsigned int)u) << 16; return v.f;
}
__device__ __forceinline__ ushort_t f2bf(float f) {  // round-to-nearest-even
    union { float f; unsigned int i; } v; v.f = f;
    unsigned int r = (v.i + 0x7FFFu + ((v.i >> 16) & 1u)) >> 16;
    return (ushort_t)r;
}

__device__ __forceinline__ void gload16(const void* g, void* l) {
    __builtin_amdgcn_global_load_lds(
        (const __attribute__((address_space(1))) unsigned int*)g,
        (__attribute__((address_space(3))) unsigned int*)l, 16, 0, 0);
}

template<int N> __device__ __forceinline__ void waitcnt_vm() {
    asm volatile("s_waitcnt vmcnt(%0)" :: "n"(N) : "memory");
}
__device__ __forceinline__ void barrier_() { asm volatile("s_barrier" ::: "memory"); }

__global__ void zero_kernel(float4* __restrict__ p, int n16) {
    int i = blockIdx.x * blockDim.x + threadIdx.x;
    if (i < n16) p[i] = make_float4(0.f, 0.f, 0.f, 0.f);
}

// ===== P = emb @ W + b_input, tiled (64x64 tiles, K=128 staged in LDS) =====
__global__ __launch_bounds__(256) void precomp_P(
    const float* __restrict__ src_emb, const float* __restrict__ tgt_emb,
    const float* __restrict__ Wf, const float* __restrict__ bf,
    const float* __restrict__ Wb, const float* __restrict__ bb,
    const float* __restrict__ Wd, const float* __restrict__ bd,
    float* __restrict__ Pf, float* __restrict__ Pb, float* __restrict__ Pd) {
    const int mat = blockIdx.z;
    const float* emb = (mat == 2) ? tgt_emb : src_emb;
    const float* W   = (mat == 0) ? Wf : (mat == 1) ? Wb : Wd;
    const float* bia = (mat == 0) ? bf : (mat == 1) ? bb : bd;
    float* P         = (mat == 0) ? Pf : (mat == 1) ? Pb : Pd;

    const int bm = blockIdx.x * 64;
    const int bn = blockIdx.y * 64;
    const int tid = threadIdx.x;
    const int tx = tid & 15;
    const int ty = tid >> 4;

    __shared__ __align__(16) float As[64][17];
    __shared__ __align__(16) float Bs[16][64];

    float acc[4][4];
#pragma unroll
    for (int i = 0; i < 4; i++)
#pragma unroll
        for (int j = 0; j < 4; j++) acc[i][j] = 0.0f;

    const int ar = tid >> 2;
    const int ak = (tid & 3) * 4;
    const int bk = tid >> 4;
    const int bc = (tid & 15) * 4;

    for (int k0 = 0; k0 < EN; k0 += 16) {
        float4 av = *reinterpret_cast<const float4*>(&emb[(bm + ar) * EN + k0 + ak]);
        As[ar][ak + 0] = av.x; As[ar][ak + 1] = av.y; As[ar][ak + 2] = av.z; As[ar][ak + 3] = av.w;
        float4 bv = *reinterpret_cast<const float4*>(&W[(k0 + bk) * GN + bn + bc]);
        *reinterpret_cast<float4*>(&Bs[bk][bc]) = bv;
        __syncthreads();
#pragma unroll
        for (int kk = 0; kk < 16; kk++) {
            float a[4];
#pragma unroll
            for (int i = 0; i < 4; i++) a[i] = As[ty * 4 + i][kk];
            float4 b4 = *reinterpret_cast<float4*>(&Bs[kk][tx * 4]);
#pragma unroll
            for (int i = 0; i < 4; i++) {
                acc[i][0] += a[i] * b4.x;
                acc[i][1] += a[i] * b4.y;
                acc[i][2] += a[i] * b4.z;
                acc[i][3] += a[i] * b4.w;
            }
        }
        __syncthreads();
    }

#pragma unroll
    for (int i = 0; i < 4; i++) {
        const int row = bm + ty * 4 + i;
#pragma unroll
        for (int j = 0; j < 4; j++) {
            const int col = bn + tx * 4 + j;
            P[(size_t)row * GN + col] = acc[i][j] + bia[col];
        }
    }
}

// Recurrent B (hi only), coalesced reads: Bt2[mat][chunk 0..15][gcol][j 0..31]
__global__ void precomp_Bt2(const float* __restrict__ Uf, const float* __restrict__ Ub,
                            const float* __restrict__ Ud,
                            ushort_t* __restrict__ BtF, ushort_t* __restrict__ BtB,
                            ushort_t* __restrict__ BtD) {
    int mat = blockIdx.x >> 4;
    int c   = blockIdx.x & 15;
    const float* U = (mat == 0) ? Uf : (mat == 1) ? Ub : Ud;
    ushort_t* Bt   = (mat == 0) ? BtF : (mat == 1) ? BtB : BtD;
    const int kb = c * 32;
    for (int j = 0; j < 32; j++) {
        for (int gcol = threadIdx.x; gcol < GN; gcol += 256) {
            Bt[((size_t)c * GN + gcol) * 32 + j] = f2bf(U[(size_t)(kb + j) * GN + gcol]);
        }
    }
}

// Logits B (3-term): Wot2[chunk 0..31][col][j]; chunk 0..15 hi, 16..31 lo. Coalesced reads.
__global__ void precomp_Wot2(const float* __restrict__ Wo, ushort_t* __restrict__ Wot) {
    int c = blockIdx.x;  // 0..31
    const int kb = (c < 16) ? c * 32 : (c - 16) * 32;
    for (int j = 0; j < 32; j++) {
        for (int col = threadIdx.x; col < VN; col += 256) {
            float u = Wo[(size_t)(kb + j) * VN + col];
            ushort_t hi = f2bf(u);
            Wot[((size_t)c * VN + col) * 32 + j] = (c >= 16) ? f2bf(u - bf2f(hi)) : hi;
        }
    }
}

__global__ void dec_init(const ushort_t* __restrict__ hf, const ushort_t* __restrict__ hb,
                         ushort_t* __restrict__ hd) {
    int i = blockIdx.x * blockDim.x + threadIdx.x;
    if (i >= BN_ * HN) return;
    int row = i >> 9, col = i & (HN - 1);
    float h = bf2f(hf[(size_t)row * HC + col]) + bf2f(hf[(size_t)row * HC + HN + col])
            + bf2f(hb[(size_t)row * HC + col]) + bf2f(hb[(size_t)row * HC + HN + col]);
    ushort_t hi = f2bf(h);
    hd[(size_t)row * HC + col] = hi;
    hd[(size_t)row * HC + HN + col] = f2bf(h - bf2f(hi));
}

// ===== Encoder step: both dirs, MT=128, 4 waves of 64x32 (NN=2). Grid (64,8). =====
// XCD = bx%8: dir = bx&4 (fwd XCD 0-3, bwd 4-7), rtile = (bx>>3)*4 + (bx&3).
// 16 chunks; per chunk stage {A-hi 8K, A-lo 8K, B 12K} (B once). PD=2, LDS 56KB,
// 2 blocks/CU. Counted vmcnt(7) = one stage (2+2+3 gloads/wave) in flight.
__global__ __launch_bounds__(256, 2) void enc_step(
    const ushort_t* __restrict__ hf_in, ushort_t* __restrict__ hf_out,
    const ushort_t* __restrict__ BtF, const float* __restrict__ brF, const float* __restrict__ Pf,
    const ushort_t* __restrict__ hb_in, ushort_t* __restrict__ hb_out,
    const ushort_t* __restrict__ BtB, const float* __restrict__ brB, const float* __restrict__ Pb,
    const int* __restrict__ src, int t) {
    const int bx = blockIdx.x;
    const ushort_t* hin; ushort_t* hout; const ushort_t* Bt; const float* brec; const float* P; int rev;
    if ((bx & 4) == 0) { hin = hf_in; hout = hf_out; Bt = BtF; brec = brF; P = Pf; rev = 0; }
    else               { hin = hb_in; hout = hb_out; Bt = BtB; brec = brB; P = Pb; rev = 1; }
    const int bm = ((bx >> 3) * 4 + (bx & 3)) * 128;
    const int bj = blockIdx.y * 64;
    const int tid = threadIdx.x;
    const int lane = tid & 63;
    const int w = tid >> 6;
    const int wr = w >> 1, wc = w & 1;

    __shared__ __align__(16) short Asm[2][256 * 32];   // rows 0..127 A-hi, 128..255 A-lo
    __shared__ __align__(16) short Bsm[2][192 * 32];

    f32x4 acc[3][4][2];
#pragma unroll
    for (int g = 0; g < 3; g++)
#pragma unroll
        for (int i = 0; i < 4; i++)
#pragma unroll
            for (int n = 0; n < 2; n++) acc[g][i][n] = (f32x4){0.f, 0.f, 0.f, 0.f};

    const int fl = lane & 15;
    const int fke = (((lane >> 4) ^ ((lane >> 1) & 3)) * 8);    // swizzled read slot
    const int lr = lane >> 2;
    const int lk = (((lane & 3) ^ ((lane >> 3) & 3)) * 8);      // swizzled global slot

    auto stage = [&](int buf, int kc) {
        const int ah = kc * 32;
        const int al = 512 + kc * 32;
#pragma unroll
        for (int s = 0; s < 2; ++s) {
            const int r0 = w * 32 + s * 16;
            gload16(hin + (size_t)(bm + r0 + lr) * HC + ah + lk, &Asm[buf][r0 * 32]);
            gload16(hin + (size_t)(bm + r0 + lr) * HC + al + lk, &Asm[buf][(128 + r0) * 32]);
        }
#pragma unroll
        for (int s = 0; s < 3; ++s) {
            const int r0 = w * 48 + s * 16;
            const int r = r0 + lr;
            const int gcol = ((r >> 6) << 9) + bj + (r & 63);
            gload16(Bt + ((size_t)kc * GN + gcol) * 32 + lk, &Bsm[buf][r0 * 32]);
        }
    };

    auto compute = [&](int cur) {
        const short* Ab = Asm[cur];
        const short* Bb = Bsm[cur];
        bf16x8 ah[4], al[4];
#pragma unroll
        for (int i = 0; i < 4; i++) {
            ah[i] = *(const bf16x8*)&Ab[(wr * 64 + i * 16 + fl) * 32 + fke];
            al[i] = *(const bf16x8*)&Ab[(128 + wr * 64 + i * 16 + fl) * 32 + fke];
        }
#pragma unroll
        for (int g = 0; g < 3; g++) {
#pragma unroll
            for (int n = 0; n < 2; n++) {
                bf16x8 bfr = *(const bf16x8*)&Bb[(g * 64 + wc * 32 + n * 16 + fl) * 32 + fke];
#pragma unroll
                for (int i = 0; i < 4; i++) {
                    acc[g][i][n] = __builtin_amdgcn_mfma_f32_16x16x32_bf16(ah[i], bfr, acc[g][i][n], 0, 0, 0);
                    acc[g][i][n] = __builtin_amdgcn_mfma_f32_16x16x32_bf16(al[i], bfr, acc[g][i][n], 0, 0, 0);
                }
            }
        }
    };

    stage(0, 0);
    for (int kc = 0; kc < 16; ++kc) {
        if (kc < 15) { stage((kc + 1) & 1, kc + 1); waitcnt_vm<7>(); }
        else         { waitcnt_vm<0>(); }
        barrier_();
        compute(kc & 1);
        barrier_();
    }

    const int fq = lane >> 4;
#pragma unroll
    for (int i = 0; i < 4; i++) {
#pragma unroll
        for (int q = 0; q < 4; q++) {
            const int row = bm + wr * 64 + i * 16 + fq * 4 + q;
            const int idx = src[row * SN + (rev ? (SN - 1 - t) : t)];
            const float* Pr = P + (size_t)idx * GN;
#pragma unroll
            for (int n = 0; n < 2; n++) {
                const int col = bj + wc * 32 + n * 16 + fl;
                float rz = acc[0][i][n][q] + brec[col];
                float rr = acc[1][i][n][q] + brec[HN + col];
                float rh = acc[2][i][n][q] + brec[2 * HN + col];
                float z = 1.f / (1.f + expf(-(Pr[col] + rz)));
                float r = 1.f / (1.f + expf(-(Pr[HN + col] + rr)));
                float hh = tanhf(Pr[2 * HN + col] + r * rh);
                float ho = bf2f(hin[(size_t)row * HC + col]) + bf2f(hin[(size_t)row * HC + HN + col]);
                float hnew = z * ho + (1.f - z) * hh;
                ushort_t hib = f2bf(hnew);
                hout[(size_t)row * HC + col] = hib;
                hout[(size_t)row * HC + HN + col] = f2bf(hnew - bf2f(hib));
            }
        }
    }
}

// ===== Fused decoder step t (16 chunks, B-once) + logits of t-1 (48 chunks, 3-term). =====
// dec buffer: A-hi rows 0..63, A-lo 64..127, B 128..319 -> 20KB/buf; LDS 40KB, 3 blocks/CU.
__global__ __launch_bounds__(256, 3) void dec_fused(
    const ushort_t* __restrict__ hin, ushort_t* __restrict__ hout,
    const ushort_t* __restrict__ BtD, const float* __restrict__ brD, const float* __restrict__ Pd,
    const int* __restrict__ tgt, const ushort_t* __restrict__ Wot,
    const float* __restrict__ bo, float* __restrict__ out, int t) {
    const int bx = blockIdx.x;
    const int tid = threadIdx.x;
    const int lane = tid & 63;
    const int w = tid >> 6;
    const int fl = lane & 15;
    const int fke = (((lane >> 4) ^ ((lane >> 1) & 3)) * 8);
    const int lr = lane >> 2;
    const int lk = (((lane & 3) ^ ((lane >> 3) & 3)) * 8);
    const int fq = lane >> 4;

    __shared__ __align__(16) short SM[2][320 * 32];

    if (bx < 512) {
        const int bm = (bx & 63) * 64;
        const int bj = (bx >> 6) * 64;

        f32x4 acc[3][4];
#pragma unroll
        for (int g = 0; g < 3; g++)
#pragma unroll
            for (int i = 0; i < 4; i++) acc[g][i] = (f32x4){0.f, 0.f, 0.f, 0.f};

        auto stage = [&](int buf, int kc) {
            const int ah = kc * 32;
            const int al = 512 + kc * 32;
            const int r0a = w * 16;
            gload16(hin + (size_t)(bm + r0a + lr) * HC + ah + lk, &SM[buf][r0a * 32]);
            gload16(hin + (size_t)(bm + r0a + lr) * HC + al + lk, &SM[buf][(64 + r0a) * 32]);
#pragma unroll
            for (int s = 0; s < 3; ++s) {
                const int r0 = w * 48 + s * 16;
                const int r = r0 + lr;
                const int gcol = ((r >> 6) << 9) + bj + (r & 63);
                gload16(BtD + ((size_t)kc * GN + gcol) * 32 + lk, &SM[buf][(128 + r0) * 32]);
            }
        };
        auto compute = [&](int cur) {
            const short* Ab = &SM[cur][0];
            const short* Bb = &SM[cur][128 * 32];
            bf16x8 ah[4], al[4];
#pragma unroll
            for (int i = 0; i < 4; i++) {
                ah[i] = *(const bf16x8*)&Ab[(i * 16 + fl) * 32 + fke];
                al[i] = *(const bf16x8*)&Ab[(64 + i * 16 + fl) * 32 + fke];
            }
#pragma unroll
            for (int g = 0; g < 3; g++) {
                bf16x8 bfr = *(const bf16x8*)&Bb[(g * 64 + w * 16 + fl) * 32 + fke];
#pragma unroll
                for (int i = 0; i < 4; i++) {
                    acc[g][i] = __builtin_amdgcn_mfma_f32_16x16x32_bf16(ah[i], bfr, acc[g][i], 0, 0, 0);
                    acc[g][i] = __builtin_amdgcn_mfma_f32_16x16x32_bf16(al[i], bfr, acc[g][i], 0, 0, 0);
                }
            }
        };

        stage(0, 0);
        for (int kc = 0; kc < 16; ++kc) {
            if (kc < 15) { stage((kc + 1) & 1, kc + 1); waitcnt_vm<5>(); }
            else         { waitcnt_vm<0>(); }
            barrier_();
            compute(kc & 1);
            barrier_();
        }

#pragma unroll
        for (int i = 0; i < 4; i++) {
#pragma unroll
            for (int q = 0; q < 4; q++) {
                const int row = bm + i * 16 + fq * 4 + q;
                const int idx = (t == 0) ? BOW_ : tgt[row * TN + (t - 1)];
                const float* Pr = Pd + (size_t)idx * GN;
                const int col = bj + w * 16 + fl;
                float rz = acc[0][i][q] + brD[col];
                float rr = acc[1][i][q] + brD[HN + col];
                float rh = acc[2][i][q] + brD[2 * HN + col];
                float z = 1.f / (1.f + expf(-(Pr[col] + rz)));
                float r = 1.f / (1.f + expf(-(Pr[HN + col] + rr)));
                float hh = tanhf(Pr[2 * HN + col] + r * rh);
                float ho = bf2f(hin[(size_t)row * HC + col]) + bf2f(hin[(size_t)row * HC + HN + col]);
                float hnew = z * ho + (1.f - z) * hh;
                ushort_t hib = f2bf(hnew);
                hout[(size_t)row * HC + col] = hib;
                hout[(size_t)row * HC + HN + col] = f2bf(hnew - bf2f(hib));
            }
        }
    } else {
        if (t == 0) return;
        const int l = bx - 512;
        const int bm = (l & 63) * 64;
        const int bn = (l >> 6) * 64;

        f32x4 acc[4];
#pragma unroll
        for (int i = 0; i < 4; i++) acc[i] = (f32x4){0.f, 0.f, 0.f, 0.f};

        // 48 chunks: 0..15 Ahi x Wohi, 16..31 Alo x Wohi, 32..47 Ahi x Wolo
        auto stage = [&](int buf, int kc) {
            const int aS = (kc < 16) ? (kc * 32) : (kc < 32) ? (512 + (kc - 16) * 32) : ((kc - 32) * 32);
            const int wfix = (kc < 32) ? (kc & 15) : (16 + (kc - 32));
            const int r0 = w * 16;
            gload16(hin + (size_t)(bm + r0 + lr) * HC + aS + lk, &SM[buf][r0 * 32]);
            gload16(Wot + ((size_t)wfix * VN + bn + r0 + lr) * 32 + lk, &SM[buf][(64 + r0) * 32]);
        };
        auto compute = [&](int cur) {
            const short* Ab = &SM[cur][0];
            const short* Bb = &SM[cur][64 * 32];
            bf16x8 bfr = *(const bf16x8*)&Bb[(w * 16 + fl) * 32 + fke];
#pragma unroll
            for (int i = 0; i < 4; i++) {
                bf16x8 af = *(const bf16x8*)&Ab[(i * 16 + fl) * 32 + fke];
                acc[i] = __builtin_amdgcn_mfma_f32_16x16x32_bf16(af, bfr, acc[i], 0, 0, 0);
            }
        };

        stage(0, 0);
        for (int kc = 0; kc < 48; ++kc) {
            if (kc < 47) { stage((kc + 1) & 1, kc + 1); waitcnt_vm<2>(); }
            else         { waitcnt_vm<0>(); }
            barrier_();
            compute(kc & 1);
            barrier_();
        }

#pragma unroll
        for (int i = 0; i < 4; i++) {
#pragma unroll
            for (int q = 0; q < 4; q++) {
                const int row = bm + i * 16 + fq * 4 + q;
                const int col = bn + w * 16 + fl;
                out[(size_t)row * (TN * VN) + (t - 1) * VN + col] = acc[i][q] + bo[col];
            }
        }
    }
}

// standalone logits for the final decoder output (t = TN-1), 3-term, 48 chunks
__global__ __launch_bounds__(256) void logits_mfma(
    const ushort_t* __restrict__ hin, const ushort_t* __restrict__ Wot,
    const float* __restrict__ bo, float* __restrict__ out, int t) {
    const int bm = blockIdx.x * 64;
    const int bn = blockIdx.y * 64;
    const int tid = threadIdx.x;
    const int lane = tid & 63;
    const int w = tid >> 6;

    __shared__ __align__(16) short Asm[2][64 * 32];
    __shared__ __align__(16) short Bsm[2][64 * 32];

    f32x4 acc[4];
#pragma unroll
    for (int i = 0; i < 4; i++) acc[i] = (f32x4){0.f, 0.f, 0.f, 0.f};

    const int fl = lane & 15;
    const int fke = (((lane >> 4) ^ ((lane >> 1) & 3)) * 8);
    const int lr = lane >> 2;
    const int lk = (((lane & 3) ^ ((lane >> 3) & 3)) * 8);

    auto stage = [&](int buf, int kc) {
        const int aS = (kc < 16) ? (kc * 32) : (kc < 32) ? (512 + (kc - 16) * 32) : ((kc - 32) * 32);
        const int wfix = (kc < 32) ? (kc & 15) : (16 + (kc - 32));
        const int r0 = w * 16;
        gload16(hin + (size_t)(bm + r0 + lr) * HC + aS + lk, &Asm[buf][r0 * 32]);
        gload16(Wot + ((size_t)wfix * VN + bn + r0 + lr) * 32 + lk, &Bsm[buf][r0 * 32]);
    };
    auto compute = [&](int cur) {
        const short* Ab = Asm[cur];
        const short* Bb = Bsm[cur];
        bf16x8 bfr = *(const bf16x8*)&Bb[(w * 16 + fl) * 32 + fke];
#pragma unroll
        for (int i = 0; i < 4; i++) {
            bf16x8 af = *(const bf16x8*)&Ab[(i * 16 + fl) * 32 + fke];
            acc[i] = __builtin_amdgcn_mfma_f32_16x16x32_bf16(af, bfr, acc[i], 0, 0, 0);
        }
    };

    stage(0, 0);
    for (int kc = 0; kc < 48; ++kc) {
        if (kc < 47) { stage((kc + 1) & 1, kc + 1); waitcnt_vm<2>(); }
        else         { waitcnt_vm<0>(); }
        barrier_();
        compute(kc & 1);
        barrier_();
    }

    const int fq = lane >> 4;
#pragma unroll
    for (int i = 0; i < 4; i++) {
#pragma unroll
        for (int q = 0; q < 4; q++) {
            const int row = bm + i * 16 + fq * 4 + q;
            const int col = bn + w * 16 + fl;
            out[(size_t)row * (TN * VN) + t * VN + col] = acc[i][q] + bo[col];
        }
    }
}

extern "C" void kernel_launch(void* const* d_in, const int* in_sizes, int n_in,
                              void* d_out, int out_size, void* d_ws, size_t ws_size,
                              hipStream_t stream) {
    const int* source    = (const int*)d_in[0];
    const int* targets   = (const int*)d_in[1];
    const float* src_emb = (const float*)d_in[2];
    const float* tgt_emb = (const float*)d_in[3];
    const float* Wf = (const float*)d_in[4];
    const float* Uf = (const float*)d_in[5];
    const float* bf = (const float*)d_in[6];
    const float* Wb = (const float*)d_in[7];
    const float* Ub = (const float*)d_in[8];
    const float* bb = (const float*)d_in[9];
    const float* Wd = (const float*)d_in[10];
    const float* Ud = (const float*)d_in[11];
    const float* bd = (const float*)d_in[12];
    const float* Wo = (const float*)d_in[13];
    const float* bo = (const float*)d_in[14];
    float* out = (float*)d_out;

    char* ws = (char*)d_ws;
    ushort_t* BtF = (ushort_t*)(ws);                    // 16*1536*32*2 = 1572864 each
    ushort_t* BtB = (ushort_t*)(ws + 1572864);
    ushort_t* BtD = (ushort_t*)(ws + 2 * 1572864);
    ushort_t* Wot = (ushort_t*)(ws + 3 * 1572864);      // 32*256*32*2 = 524288
    float*    Pf  = (float*)   (ws + 3 * 1572864 + 524288);  // 3*256*1536*4 = 4718592
    float*    Pb  = Pf + VN * GN;
    float*    Pd  = Pb + VN * GN;
    char* hbase = ws + 3 * 1572864 + 524288 + 4718592;  // 4 x 4096*1024*2 = 4 x 8388608
    ushort_t* hf0 = (ushort_t*)(hbase);
    ushort_t* hf1 = (ushort_t*)(hbase + 8388608);
    ushort_t* hb0 = (ushort_t*)(hbase + 2 * 8388608);
    ushort_t* hb1 = (ushort_t*)(hbase + 3 * 8388608);

    zero_kernel<<<2048, 256, 0, stream>>>((float4*)hf0, 524288);
    zero_kernel<<<2048, 256, 0, stream>>>((float4*)hb0, 524288);
    precomp_P<<<dim3(4, 24, 3), 256, 0, stream>>>(src_emb, tgt_emb, Wf, bf, Wb, bb, Wd, bd, Pf, Pb, Pd);
    precomp_Bt2<<<48, 256, 0, stream>>>(Uf, Ub, Ud, BtF, BtB, BtD);
    precomp_Wot2<<<32, 256, 0, stream>>>(Wo, Wot);

    // encoder: grid (64,8): XCD 0-3 fwd / 4-7 bwd, 128-row tiles, 2 blocks/CU
    for (int t = 0; t < SN; t++) {
        const ushort_t* hfi = (t & 1) ? hf1 : hf0; ushort_t* hfo = (t & 1) ? hf0 : hf1;
        const ushort_t* hbi = (t & 1) ? hb1 : hb0; ushort_t* hbo = (t & 1) ? hb0 : hb1;
        enc_step<<<dim3(64, 8), 256, 0, stream>>>(
            hfi, hfo, BtF, bf + GN, Pf,
            hbi, hbo, BtB, bb + GN, Pb,
            source, t);
    }
    dec_init<<<(BN_ * HN + 255) / 256, 256, 0, stream>>>(hf0, hb0, hb1);

    // fused decoder step t + logits(t-1); ping-pong hb1 <-> hf1
    for (int t = 0; t < TN; t++) {
        const ushort_t* hdi = (t & 1) ? hf1 : hb1; ushort_t* hdo = (t & 1) ? hb1 : hf1;
        dec_fused<<<768, 256, 0, stream>>>(
            hdi, hdo, BtD, bd + GN, Pd, targets, Wot, bo, out, t);
    }
    // final logits for t = 23 output (hdo of t=23 is hb1 since 23 is odd)
    logits_mfma<<<dim3(64, 4), 256, 0, stream>>>(hb1, Wot, bo, out, TN - 1);
}

// Round 15
// 1925.892 us; speedup vs baseline: 1.6711x; 1.0371x over previous
//
#include <hip/hip_runtime.h>
#include <math.h>

typedef unsigned short ushort_t;
typedef short bf16x8 __attribute__((ext_vector_type(8)));   // 8 bf16 = 4 VGPRs (MFMA A/B frag)
typedef float f32x4 __attribute__((ext_vector_type(4)));    // MFMA C/D frag

#define BN_ 4096
#define SN 24
#define TN 24
#define EN 128
#define HN 512
#define GN 1536
#define VN 256
#define BOW_ 1
#define HC 1024   // hcat row stride: [hi(512) | lo(512)]
// Recurrent GEMMs: 2-term split, 16 chunks of BK=32, B STAGED ONCE per chunk:
//   per kc: stage {A-hi(k=kc*32), A-lo(k=512+kc*32), B chunk kc}; acc += Ahi x B + Alo x B.
// Logits: 3-term split, 48 chunks of BK=32:
//   kc 0..15  : Ahi(k=kc*32)          x Wohi chunk kc
//   kc 16..31 : Alo(k=512+(kc-16)*32) x Wohi chunk kc-16
//   kc 32..47 : Ahi(k=(kc-32)*32)     x Wolo chunk 16+(kc-32)

__device__ __forceinline__ float bf2f(ushort_t u) {
    union { unsigned int i; float f; } v; v.i = ((unsigned int)u) << 16; return v.f;
}
__device__ __forceinline__ ushort_t f2bf(float f) {  // round-to-nearest-even
    union { float f; unsigned int i; } v; v.f = f;
    unsigned int r = (v.i + 0x7FFFu + ((v.i >> 16) & 1u)) >> 16;
    return (ushort_t)r;
}

__device__ __forceinline__ void gload16(const void* g, void* l) {
    __builtin_amdgcn_global_load_lds(
        (const __attribute__((address_space(1))) unsigned int*)g,
        (__attribute__((address_space(3))) unsigned int*)l, 16, 0, 0);
}

template<int N> __device__ __forceinline__ void waitcnt_vm() {
    asm volatile("s_waitcnt vmcnt(%0)" :: "n"(N) : "memory");
}
__device__ __forceinline__ void barrier_() { asm volatile("s_barrier" ::: "memory"); }

__global__ void zero_kernel(float4* __restrict__ p, int n16) {
    int i = blockIdx.x * blockDim.x + threadIdx.x;
    if (i < n16) p[i] = make_float4(0.f, 0.f, 0.f, 0.f);
}

// ===== P = emb @ W + b_input, tiled (64x64 tiles, K=128 staged in LDS) =====
__global__ __launch_bounds__(256) void precomp_P(
    const float* __restrict__ src_emb, const float* __restrict__ tgt_emb,
    const float* __restrict__ Wf, const float* __restrict__ bf,
    const float* __restrict__ Wb, const float* __restrict__ bb,
    const float* __restrict__ Wd, const float* __restrict__ bd,
    float* __restrict__ Pf, float* __restrict__ Pb, float* __restrict__ Pd) {
    const int mat = blockIdx.z;
    const float* emb = (mat == 2) ? tgt_emb : src_emb;
    const float* W   = (mat == 0) ? Wf : (mat == 1) ? Wb : Wd;
    const float* bia = (mat == 0) ? bf : (mat == 1) ? bb : bd;
    float* P         = (mat == 0) ? Pf : (mat == 1) ? Pb : Pd;

    const int bm = blockIdx.x * 64;
    const int bn = blockIdx.y * 64;
    const int tid = threadIdx.x;
    const int tx = tid & 15;
    const int ty = tid >> 4;

    __shared__ __align__(16) float As[64][17];
    __shared__ __align__(16) float Bs[16][64];

    float acc[4][4];
#pragma unroll
    for (int i = 0; i < 4; i++)
#pragma unroll
        for (int j = 0; j < 4; j++) acc[i][j] = 0.0f;

    const int ar = tid >> 2;
    const int ak = (tid & 3) * 4;
    const int bk = tid >> 4;
    const int bc = (tid & 15) * 4;

    for (int k0 = 0; k0 < EN; k0 += 16) {
        float4 av = *reinterpret_cast<const float4*>(&emb[(bm + ar) * EN + k0 + ak]);
        As[ar][ak + 0] = av.x; As[ar][ak + 1] = av.y; As[ar][ak + 2] = av.z; As[ar][ak + 3] = av.w;
        float4 bv = *reinterpret_cast<const float4*>(&W[(k0 + bk) * GN + bn + bc]);
        *reinterpret_cast<float4*>(&Bs[bk][bc]) = bv;
        __syncthreads();
#pragma unroll
        for (int kk = 0; kk < 16; kk++) {
            float a[4];
#pragma unroll
            for (int i = 0; i < 4; i++) a[i] = As[ty * 4 + i][kk];
            float4 b4 = *reinterpret_cast<float4*>(&Bs[kk][tx * 4]);
#pragma unroll
            for (int i = 0; i < 4; i++) {
                acc[i][0] += a[i] * b4.x;
                acc[i][1] += a[i] * b4.y;
                acc[i][2] += a[i] * b4.z;
                acc[i][3] += a[i] * b4.w;
            }
        }
        __syncthreads();
    }

#pragma unroll
    for (int i = 0; i < 4; i++) {
        const int row = bm + ty * 4 + i;
#pragma unroll
        for (int j = 0; j < 4; j++) {
            const int col = bn + tx * 4 + j;
            P[(size_t)row * GN + col] = acc[i][j] + bia[col];
        }
    }
}

// Recurrent B (hi only) via LDS tile transpose, both sides coalesced.
// Bt2[mat][chunk 0..15][gcol][j 0..31] = bf16hi(U[chunk*32+j][gcol]). grid (24,16,3).
__global__ __launch_bounds__(256) void precomp_Bt2(
    const float* __restrict__ Uf, const float* __restrict__ Ub, const float* __restrict__ Ud,
    ushort_t* __restrict__ BtF, ushort_t* __restrict__ BtB, ushort_t* __restrict__ BtD) {
    const int mat = blockIdx.z;
    const float* U = (mat == 0) ? Uf : (mat == 1) ? Ub : Ud;
    ushort_t* Bt   = (mat == 0) ? BtF : (mat == 1) ? BtB : BtD;
    const int c  = blockIdx.y;          // chunk
    const int ct = blockIdx.x * 64;     // gcol tile
    const int kb = c * 32;

    __shared__ float tile[32][65];
    const int gc = threadIdx.x & 63;
    const int j0 = threadIdx.x >> 6;    // 0..3
#pragma unroll
    for (int s = 0; s < 8; ++s) {
        const int j = j0 * 8 + s;
        tile[j][gc] = U[(size_t)(kb + j) * GN + ct + gc];
    }
    __syncthreads();
    const int j  = threadIdx.x & 31;
    const int g0 = threadIdx.x >> 5;    // 0..7
#pragma unroll
    for (int p = 0; p < 8; ++p) {
        const int gcl = p * 8 + g0;     // 8 consecutive gcols per iteration
        Bt[((size_t)c * GN + ct + gcl) * 32 + j] = f2bf(tile[j][gcl]);
    }
}

// Logits B (3-term) via LDS tile transpose: Wot2[chunk 0..31][col][j]; 0..15 hi, 16..31 lo.
// grid (4, 32).
__global__ __launch_bounds__(256) void precomp_Wot2(
    const float* __restrict__ Wo, ushort_t* __restrict__ Wot) {
    const int c  = blockIdx.y;          // 0..31
    const int ct = blockIdx.x * 64;
    const int kb = (c < 16) ? c * 32 : (c - 16) * 32;

    __shared__ float tile[32][65];
    const int gc = threadIdx.x & 63;
    const int j0 = threadIdx.x >> 6;
#pragma unroll
    for (int s = 0; s < 8; ++s) {
        const int j = j0 * 8 + s;
        tile[j][gc] = Wo[(size_t)(kb + j) * VN + ct + gc];
    }
    __syncthreads();
    const int j  = threadIdx.x & 31;
    const int g0 = threadIdx.x >> 5;
#pragma unroll
    for (int p = 0; p < 8; ++p) {
        const int gcl = p * 8 + g0;
        float u = tile[j][gcl];
        ushort_t hi = f2bf(u);
        Wot[((size_t)c * VN + ct + gcl) * 32 + j] = (c >= 16) ? f2bf(u - bf2f(hi)) : hi;
    }
}

__global__ void dec_init(const ushort_t* __restrict__ hf, const ushort_t* __restrict__ hb,
                         ushort_t* __restrict__ hd) {
    int i = blockIdx.x * blockDim.x + threadIdx.x;
    if (i >= BN_ * HN) return;
    int row = i >> 9, col = i & (HN - 1);
    float h = bf2f(hf[(size_t)row * HC + col]) + bf2f(hf[(size_t)row * HC + HN + col])
            + bf2f(hb[(size_t)row * HC + col]) + bf2f(hb[(size_t)row * HC + HN + col]);
    ushort_t hi = f2bf(h);
    hd[(size_t)row * HC + col] = hi;
    hd[(size_t)row * HC + HN + col] = f2bf(h - bf2f(hi));
}

// ===== Encoder step: both dirs, MT=128, 4 waves of 64x32 (NN=2). Grid (64,8). =====
// XCD = bx%8: dir = bx&4 (fwd XCD 0-3, bwd 4-7), rtile = (bx>>3)*4 + (bx&3).
// 16 chunks; per chunk stage {A-hi 8K, A-lo 8K, B 12K} (B once). PD=2, LDS 56KB,
// 2 blocks/CU. Counted vmcnt(7) = one stage (2+2+3 gloads/wave) in flight.
__global__ __launch_bounds__(256, 2) void enc_step(
    const ushort_t* __restrict__ hf_in, ushort_t* __restrict__ hf_out,
    const ushort_t* __restrict__ BtF, const float* __restrict__ brF, const float* __restrict__ Pf,
    const ushort_t* __restrict__ hb_in, ushort_t* __restrict__ hb_out,
    const ushort_t* __restrict__ BtB, const float* __restrict__ brB, const float* __restrict__ Pb,
    const int* __restrict__ src, int t) {
    const int bx = blockIdx.x;
    const ushort_t* hin; ushort_t* hout; const ushort_t* Bt; const float* brec; const float* P; int rev;
    if ((bx & 4) == 0) { hin = hf_in; hout = hf_out; Bt = BtF; brec = brF; P = Pf; rev = 0; }
    else               { hin = hb_in; hout = hb_out; Bt = BtB; brec = brB; P = Pb; rev = 1; }
    const int bm = ((bx >> 3) * 4 + (bx & 3)) * 128;
    const int bj = blockIdx.y * 64;
    const int tid = threadIdx.x;
    const int lane = tid & 63;
    const int w = tid >> 6;
    const int wr = w >> 1, wc = w & 1;

    __shared__ __align__(16) short Asm[2][256 * 32];   // rows 0..127 A-hi, 128..255 A-lo
    __shared__ __align__(16) short Bsm[2][192 * 32];

    f32x4 acc[3][4][2];
#pragma unroll
    for (int g = 0; g < 3; g++)
#pragma unroll
        for (int i = 0; i < 4; i++)
#pragma unroll
            for (int n = 0; n < 2; n++) acc[g][i][n] = (f32x4){0.f, 0.f, 0.f, 0.f};

    const int fl = lane & 15;
    const int fke = (((lane >> 4) ^ ((lane >> 1) & 3)) * 8);    // swizzled read slot
    const int lr = lane >> 2;
    const int lk = (((lane & 3) ^ ((lane >> 3) & 3)) * 8);      // swizzled global slot

    auto stage = [&](int buf, int kc) {
        const int ah = kc * 32;
        const int al = 512 + kc * 32;
#pragma unroll
        for (int s = 0; s < 2; ++s) {
            const int r0 = w * 32 + s * 16;
            gload16(hin + (size_t)(bm + r0 + lr) * HC + ah + lk, &Asm[buf][r0 * 32]);
            gload16(hin + (size_t)(bm + r0 + lr) * HC + al + lk, &Asm[buf][(128 + r0) * 32]);
        }
#pragma unroll
        for (int s = 0; s < 3; ++s) {
            const int r0 = w * 48 + s * 16;
            const int r = r0 + lr;
            const int gcol = ((r >> 6) << 9) + bj + (r & 63);
            gload16(Bt + ((size_t)kc * GN + gcol) * 32 + lk, &Bsm[buf][r0 * 32]);
        }
    };

    auto compute = [&](int cur) {
        const short* Ab = Asm[cur];
        const short* Bb = Bsm[cur];
        bf16x8 ah[4], al[4];
#pragma unroll
        for (int i = 0; i < 4; i++) {
            ah[i] = *(const bf16x8*)&Ab[(wr * 64 + i * 16 + fl) * 32 + fke];
            al[i] = *(const bf16x8*)&Ab[(128 + wr * 64 + i * 16 + fl) * 32 + fke];
        }
#pragma unroll
        for (int g = 0; g < 3; g++) {
#pragma unroll
            for (int n = 0; n < 2; n++) {
                bf16x8 bfr = *(const bf16x8*)&Bb[(g * 64 + wc * 32 + n * 16 + fl) * 32 + fke];
#pragma unroll
                for (int i = 0; i < 4; i++) {
                    acc[g][i][n] = __builtin_amdgcn_mfma_f32_16x16x32_bf16(ah[i], bfr, acc[g][i][n], 0, 0, 0);
                    acc[g][i][n] = __builtin_amdgcn_mfma_f32_16x16x32_bf16(al[i], bfr, acc[g][i][n], 0, 0, 0);
                }
            }
        }
    };

    stage(0, 0);
    for (int kc = 0; kc < 16; ++kc) {
        if (kc < 15) { stage((kc + 1) & 1, kc + 1); waitcnt_vm<7>(); }
        else         { waitcnt_vm<0>(); }
        barrier_();
        compute(kc & 1);
        barrier_();
    }

    const int fq = lane >> 4;
#pragma unroll
    for (int i = 0; i < 4; i++) {
#pragma unroll
        for (int q = 0; q < 4; q++) {
            const int row = bm + wr * 64 + i * 16 + fq * 4 + q;
            const int idx = src[row * SN + (rev ? (SN - 1 - t) : t)];
            const float* Pr = P + (size_t)idx * GN;
#pragma unroll
            for (int n = 0; n < 2; n++) {
                const int col = bj + wc * 32 + n * 16 + fl;
                float rz = acc[0][i][n][q] + brec[col];
                float rr = acc[1][i][n][q] + brec[HN + col];
                float rh = acc[2][i][n][q] + brec[2 * HN + col];
                float z = 1.f / (1.f + expf(-(Pr[col] + rz)));
                float r = 1.f / (1.f + expf(-(Pr[HN + col] + rr)));
                float hh = tanhf(Pr[2 * HN + col] + r * rh);
                float ho = bf2f(hin[(size_t)row * HC + col]) + bf2f(hin[(size_t)row * HC + HN + col]);
                float hnew = z * ho + (1.f - z) * hh;
                ushort_t hib = f2bf(hnew);
                hout[(size_t)row * HC + col] = hib;
                hout[(size_t)row * HC + HN + col] = f2bf(hnew - bf2f(hib));
            }
        }
    }
}

// ===== Fused decoder step t (16 chunks, B-once) + logits of t-1 (48 chunks, 3-term). =====
// dec buffer: A-hi rows 0..63, A-lo 64..127, B 128..319 -> 20KB/buf; LDS 40KB, 3 blocks/CU.
__global__ __launch_bounds__(256, 3) void dec_fused(
    const ushort_t* __restrict__ hin, ushort_t* __restrict__ hout,
    const ushort_t* __restrict__ BtD, const float* __restrict__ brD, const float* __restrict__ Pd,
    const int* __restrict__ tgt, const ushort_t* __restrict__ Wot,
    const float* __restrict__ bo, float* __restrict__ out, int t) {
    const int bx = blockIdx.x;
    const int tid = threadIdx.x;
    const int lane = tid & 63;
    const int w = tid >> 6;
    const int fl = lane & 15;
    const int fke = (((lane >> 4) ^ ((lane >> 1) & 3)) * 8);
    const int lr = lane >> 2;
    const int lk = (((lane & 3) ^ ((lane >> 3) & 3)) * 8);
    const int fq = lane >> 4;

    __shared__ __align__(16) short SM[2][320 * 32];

    if (bx < 512) {
        const int bm = (bx & 63) * 64;
        const int bj = (bx >> 6) * 64;

        f32x4 acc[3][4];
#pragma unroll
        for (int g = 0; g < 3; g++)
#pragma unroll
            for (int i = 0; i < 4; i++) acc[g][i] = (f32x4){0.f, 0.f, 0.f, 0.f};

        auto stage = [&](int buf, int kc) {
            const int ah = kc * 32;
            const int al = 512 + kc * 32;
            const int r0a = w * 16;
            gload16(hin + (size_t)(bm + r0a + lr) * HC + ah + lk, &SM[buf][r0a * 32]);
            gload16(hin + (size_t)(bm + r0a + lr) * HC + al + lk, &SM[buf][(64 + r0a) * 32]);
#pragma unroll
            for (int s = 0; s < 3; ++s) {
                const int r0 = w * 48 + s * 16;
                const int r = r0 + lr;
                const int gcol = ((r >> 6) << 9) + bj + (r & 63);
                gload16(BtD + ((size_t)kc * GN + gcol) * 32 + lk, &SM[buf][(128 + r0) * 32]);
            }
        };
        auto compute = [&](int cur) {
            const short* Ab = &SM[cur][0];
            const short* Bb = &SM[cur][128 * 32];
            bf16x8 ah[4], al[4];
#pragma unroll
            for (int i = 0; i < 4; i++) {
                ah[i] = *(const bf16x8*)&Ab[(i * 16 + fl) * 32 + fke];
                al[i] = *(const bf16x8*)&Ab[(64 + i * 16 + fl) * 32 + fke];
            }
#pragma unroll
            for (int g = 0; g < 3; g++) {
                bf16x8 bfr = *(const bf16x8*)&Bb[(g * 64 + w * 16 + fl) * 32 + fke];
#pragma unroll
                for (int i = 0; i < 4; i++) {
                    acc[g][i] = __builtin_amdgcn_mfma_f32_16x16x32_bf16(ah[i], bfr, acc[g][i], 0, 0, 0);
                    acc[g][i] = __builtin_amdgcn_mfma_f32_16x16x32_bf16(al[i], bfr, acc[g][i], 0, 0, 0);
                }
            }
        };

        stage(0, 0);
        for (int kc = 0; kc < 16; ++kc) {
            if (kc < 15) { stage((kc + 1) & 1, kc + 1); waitcnt_vm<5>(); }
            else         { waitcnt_vm<0>(); }
            barrier_();
            compute(kc & 1);
            barrier_();
        }

#pragma unroll
        for (int i = 0; i < 4; i++) {
#pragma unroll
            for (int q = 0; q < 4; q++) {
                const int row = bm + i * 16 + fq * 4 + q;
                const int idx = (t == 0) ? BOW_ : tgt[row * TN + (t - 1)];
                const float* Pr = Pd + (size_t)idx * GN;
                const int col = bj + w * 16 + fl;
                float rz = acc[0][i][q] + brD[col];
                float rr = acc[1][i][q] + brD[HN + col];
                float rh = acc[2][i][q] + brD[2 * HN + col];
                float z = 1.f / (1.f + expf(-(Pr[col] + rz)));
                float r = 1.f / (1.f + expf(-(Pr[HN + col] + rr)));
                float hh = tanhf(Pr[2 * HN + col] + r * rh);
                float ho = bf2f(hin[(size_t)row * HC + col]) + bf2f(hin[(size_t)row * HC + HN + col]);
                float hnew = z * ho + (1.f - z) * hh;
                ushort_t hib = f2bf(hnew);
                hout[(size_t)row * HC + col] = hib;
                hout[(size_t)row * HC + HN + col] = f2bf(hnew - bf2f(hib));
            }
        }
    } else {
        if (t == 0) return;
        const int l = bx - 512;
        const int bm = (l & 63) * 64;
        const int bn = (l >> 6) * 64;

        f32x4 acc[4];
#pragma unroll
        for (int i = 0; i < 4; i++) acc[i] = (f32x4){0.f, 0.f, 0.f, 0.f};

        // 48 chunks: 0..15 Ahi x Wohi, 16..31 Alo x Wohi, 32..47 Ahi x Wolo
        auto stage = [&](int buf, int kc) {
            const int aS = (kc < 16) ? (kc * 32) : (kc < 32) ? (512 + (kc - 16) * 32) : ((kc - 32) * 32);
            const int wfix = (kc < 32) ? (kc & 15) : (16 + (kc - 32));
            const int r0 = w * 16;
            gload16(hin + (size_t)(bm + r0 + lr) * HC + aS + lk, &SM[buf][r0 * 32]);
            gload16(Wot + ((size_t)wfix * VN + bn + r0 + lr) * 32 + lk, &SM[buf][(64 + r0) * 32]);
        };
        auto compute = [&](int cur) {
            const short* Ab = &SM[cur][0];
            const short* Bb = &SM[cur][64 * 32];
            bf16x8 bfr = *(const bf16x8*)&Bb[(w * 16 + fl) * 32 + fke];
#pragma unroll
            for (int i = 0; i < 4; i++) {
                bf16x8 af = *(const bf16x8*)&Ab[(i * 16 + fl) * 32 + fke];
                acc[i] = __builtin_amdgcn_mfma_f32_16x16x32_bf16(af, bfr, acc[i], 0, 0, 0);
            }
        };

        stage(0, 0);
        for (int kc = 0; kc < 48; ++kc) {
            if (kc < 47) { stage((kc + 1) & 1, kc + 1); waitcnt_vm<2>(); }
            else         { waitcnt_vm<0>(); }
            barrier_();
            compute(kc & 1);
            barrier_();
        }

#pragma unroll
        for (int i = 0; i < 4; i++) {
#pragma unroll
            for (int q = 0; q < 4; q++) {
                const int row = bm + i * 16 + fq * 4 + q;
                const int col = bn + w * 16 + fl;
                out[(size_t)row * (TN * VN) + (t - 1) * VN + col] = acc[i][q] + bo[col];
            }
        }
    }
}

// standalone logits for the final decoder output (t = TN-1), 3-term, 48 chunks
__global__ __launch_bounds__(256) void logits_mfma(
    const ushort_t* __restrict__ hin, const ushort_t* __restrict__ Wot,
    const float* __restrict__ bo, float* __restrict__ out, int t) {
    const int bm = blockIdx.x * 64;
    const int bn = blockIdx.y * 64;
    const int tid = threadIdx.x;
    const int lane = tid & 63;
    const int w = tid >> 6;

    __shared__ __align__(16) short Asm[2][64 * 32];
    __shared__ __align__(16) short Bsm[2][64 * 32];

    f32x4 acc[4];
#pragma unroll
    for (int i = 0; i < 4; i++) acc[i] = (f32x4){0.f, 0.f, 0.f, 0.f};

    const int fl = lane & 15;
    const int fke = (((lane >> 4) ^ ((lane >> 1) & 3)) * 8);
    const int lr = lane >> 2;
    const int lk = (((lane & 3) ^ ((lane >> 3) & 3)) * 8);

    auto stage = [&](int buf, int kc) {
        const int aS = (kc < 16) ? (kc * 32) : (kc < 32) ? (512 + (kc - 16) * 32) : ((kc - 32) * 32);
        const int wfix = (kc < 32) ? (kc & 15) : (16 + (kc - 32));
        const int r0 = w * 16;
        gload16(hin + (size_t)(bm + r0 + lr) * HC + aS + lk, &Asm[buf][r0 * 32]);
        gload16(Wot + ((size_t)wfix * VN + bn + r0 + lr) * 32 + lk, &Bsm[buf][r0 * 32]);
    };
    auto compute = [&](int cur) {
        const short* Ab = Asm[cur];
        const short* Bb = Bsm[cur];
        bf16x8 bfr = *(const bf16x8*)&Bb[(w * 16 + fl) * 32 + fke];
#pragma unroll
        for (int i = 0; i < 4; i++) {
            bf16x8 af = *(const bf16x8*)&Ab[(i * 16 + fl) * 32 + fke];
            acc[i] = __builtin_amdgcn_mfma_f32_16x16x32_bf16(af, bfr, acc[i], 0, 0, 0);
        }
    };

    stage(0, 0);
    for (int kc = 0; kc < 48; ++kc) {
        if (kc < 47) { stage((kc + 1) & 1, kc + 1); waitcnt_vm<2>(); }
        else         { waitcnt_vm<0>(); }
        barrier_();
        compute(kc & 1);
        barrier_();
    }

    const int fq = lane >> 4;
#pragma unroll
    for (int i = 0; i < 4; i++) {
#pragma unroll
        for (int q = 0; q < 4; q++) {
            const int row = bm + i * 16 + fq * 4 + q;
            const int col = bn + w * 16 + fl;
            out[(size_t)row * (TN * VN) + t * VN + col] = acc[i][q] + bo[col];
        }
    }
}

extern "C" void kernel_launch(void* const* d_in, const int* in_sizes, int n_in,
                              void* d_out, int out_size, void* d_ws, size_t ws_size,
                              hipStream_t stream) {
    const int* source    = (const int*)d_in[0];
    const int* targets   = (const int*)d_in[1];
    const float* src_emb = (const float*)d_in[2];
    const float* tgt_emb = (const float*)d_in[3];
    const float* Wf = (const float*)d_in[4];
    const float* Uf = (const float*)d_in[5];
    const float* bf = (const float*)d_in[6];
    const float* Wb = (const float*)d_in[7];
    const float* Ub = (const float*)d_in[8];
    const float* bb = (const float*)d_in[9];
    const float* Wd = (const float*)d_in[10];
    const float* Ud = (const float*)d_in[11];
    const float* bd = (const float*)d_in[12];
    const float* Wo = (const float*)d_in[13];
    const float* bo = (const float*)d_in[14];
    float* out = (float*)d_out;

    char* ws = (char*)d_ws;
    ushort_t* BtF = (ushort_t*)(ws);                    // 16*1536*32*2 = 1572864 each
    ushort_t* BtB = (ushort_t*)(ws + 1572864);
    ushort_t* BtD = (ushort_t*)(ws + 2 * 1572864);
    ushort_t* Wot = (ushort_t*)(ws + 3 * 1572864);      // 32*256*32*2 = 524288
    float*    Pf  = (float*)   (ws + 3 * 1572864 + 524288);  // 3*256*1536*4 = 4718592
    float*    Pb  = Pf + VN * GN;
    float*    Pd  = Pb + VN * GN;
    char* hbase = ws + 3 * 1572864 + 524288 + 4718592;  // 4 x 4096*1024*2 = 4 x 8388608
    ushort_t* hf0 = (ushort_t*)(hbase);
    ushort_t* hf1 = (ushort_t*)(hbase + 8388608);
    ushort_t* hb0 = (ushort_t*)(hbase + 2 * 8388608);
    ushort_t* hb1 = (ushort_t*)(hbase + 3 * 8388608);

    zero_kernel<<<2048, 256, 0, stream>>>((float4*)hf0, 524288);
    zero_kernel<<<2048, 256, 0, stream>>>((float4*)hb0, 524288);
    precomp_P<<<dim3(4, 24, 3), 256, 0, stream>>>(src_emb, tgt_emb, Wf, bf, Wb, bb, Wd, bd, Pf, Pb, Pd);
    precomp_Bt2<<<dim3(24, 16, 3), 256, 0, stream>>>(Uf, Ub, Ud, BtF, BtB, BtD);
    precomp_Wot2<<<dim3(4, 32), 256, 0, stream>>>(Wo, Wot);

    // encoder: grid (64,8): XCD 0-3 fwd / 4-7 bwd, 128-row tiles, 2 blocks/CU
    for (int t = 0; t < SN; t++) {
        const ushort_t* hfi = (t & 1) ? hf1 : hf0; ushort_t* hfo = (t & 1) ? hf0 : hf1;
        const ushort_t* hbi = (t & 1) ? hb1 : hb0; ushort_t* hbo = (t & 1) ? hb0 : hb1;
        enc_step<<<dim3(64, 8), 256, 0, stream>>>(
            hfi, hfo, BtF, bf + GN, Pf,
            hbi, hbo, BtB, bb + GN, Pb,
            source, t);
    }
    dec_init<<<(BN_ * HN + 255) / 256, 256, 0, stream>>>(hf0, hb0, hb1);

    // fused decoder step t + logits(t-1); ping-pong hb1 <-> hf1
    for (int t = 0; t < TN; t++) {
        const ushort_t* hdi = (t & 1) ? hf1 : hb1; ushort_t* hdo = (t & 1) ? hb1 : hf1;
        dec_fused<<<768, 256, 0, stream>>>(
            hdi, hdo, BtD, bd + GN, Pd, targets, Wot, bo, out, t);
    }
    // final logits for t = 23 output (hdo of t=23 is hb1 since 23 is odd)
    logits_mfma<<<dim3(64, 4), 256, 0, stream>>>(hb1, Wot, bo, out, TN - 1);
}

// Round 16
// 1852.587 us; speedup vs baseline: 1.7372x; 1.0396x over previous
//
#include <hip/hip_runtime.h>
#include <math.h>

typedef unsigned short ushort_t;
typedef short bf16x8 __attribute__((ext_vector_type(8)));   // 8 bf16 = 4 VGPRs (MFMA A/B frag)
typedef float f32x4 __attribute__((ext_vector_type(4)));    // MFMA C/D frag

#define BN_ 4096
#define SN 24
#define TN 24
#define EN 128
#define HN 512
#define GN 1536
#define VN 256
#define BOW_ 1
#define HC 1024   // hcat row stride: [hi(512) | lo(512)]
// Recurrent GEMMs: 2-term split, 16 chunks of BK=32, B STAGED ONCE per chunk:
//   per kc: stage {A-hi(k=kc*32), A-lo(k=512+kc*32), B chunk kc}; acc += Ahi x B + Alo x B.
// Logits: 3-term split, 48 chunks of BK=32 (Ahi x Wohi, Alo x Wohi, Ahi x Wolo).

__device__ __forceinline__ float bf2f(ushort_t u) {
    union { unsigned int i; float f; } v; v.i = ((unsigned int)u) << 16; return v.f;
}
__device__ __forceinline__ ushort_t f2bf(float f) {  // round-to-nearest-even
    union { float f; unsigned int i; } v; v.f = f;
    unsigned int r = (v.i + 0x7FFFu + ((v.i >> 16) & 1u)) >> 16;
    return (ushort_t)r;
}

__device__ __forceinline__ void gload16(const void* g, void* l) {
    __builtin_amdgcn_global_load_lds(
        (const __attribute__((address_space(1))) unsigned int*)g,
        (__attribute__((address_space(3))) unsigned int*)l, 16, 0, 0);
}

template<int N> __device__ __forceinline__ void waitcnt_vm() {
    asm volatile("s_waitcnt vmcnt(%0)" :: "n"(N) : "memory");
}
__device__ __forceinline__ void barrier_() { asm volatile("s_barrier" ::: "memory"); }

// ===== P = emb @ W + b_input, tiled (64x64 tiles, K=128 staged in LDS) =====
__global__ __launch_bounds__(256) void precomp_P(
    const float* __restrict__ src_emb, const float* __restrict__ tgt_emb,
    const float* __restrict__ Wf, const float* __restrict__ bf,
    const float* __restrict__ Wb, const float* __restrict__ bb,
    const float* __restrict__ Wd, const float* __restrict__ bd,
    float* __restrict__ Pf, float* __restrict__ Pb, float* __restrict__ Pd) {
    const int mat = blockIdx.z;
    const float* emb = (mat == 2) ? tgt_emb : src_emb;
    const float* W   = (mat == 0) ? Wf : (mat == 1) ? Wb : Wd;
    const float* bia = (mat == 0) ? bf : (mat == 1) ? bb : bd;
    float* P         = (mat == 0) ? Pf : (mat == 1) ? Pb : Pd;

    const int bm = blockIdx.x * 64;
    const int bn = blockIdx.y * 64;
    const int tid = threadIdx.x;
    const int tx = tid & 15;
    const int ty = tid >> 4;

    __shared__ __align__(16) float As[64][17];
    __shared__ __align__(16) float Bs[16][64];

    float acc[4][4];
#pragma unroll
    for (int i = 0; i < 4; i++)
#pragma unroll
        for (int j = 0; j < 4; j++) acc[i][j] = 0.0f;

    const int ar = tid >> 2;
    const int ak = (tid & 3) * 4;
    const int bk = tid >> 4;
    const int bc = (tid & 15) * 4;

    for (int k0 = 0; k0 < EN; k0 += 16) {
        float4 av = *reinterpret_cast<const float4*>(&emb[(bm + ar) * EN + k0 + ak]);
        As[ar][ak + 0] = av.x; As[ar][ak + 1] = av.y; As[ar][ak + 2] = av.z; As[ar][ak + 3] = av.w;
        float4 bv = *reinterpret_cast<const float4*>(&W[(k0 + bk) * GN + bn + bc]);
        *reinterpret_cast<float4*>(&Bs[bk][bc]) = bv;
        __syncthreads();
#pragma unroll
        for (int kk = 0; kk < 16; kk++) {
            float a[4];
#pragma unroll
            for (int i = 0; i < 4; i++) a[i] = As[ty * 4 + i][kk];
            float4 b4 = *reinterpret_cast<float4*>(&Bs[kk][tx * 4]);
#pragma unroll
            for (int i = 0; i < 4; i++) {
                acc[i][0] += a[i] * b4.x;
                acc[i][1] += a[i] * b4.y;
                acc[i][2] += a[i] * b4.z;
                acc[i][3] += a[i] * b4.w;
            }
        }
        __syncthreads();
    }

#pragma unroll
    for (int i = 0; i < 4; i++) {
        const int row = bm + ty * 4 + i;
#pragma unroll
        for (int j = 0; j < 4; j++) {
            const int col = bn + tx * 4 + j;
            P[(size_t)row * GN + col] = acc[i][j] + bia[col];
        }
    }
}

// Recurrent B (hi only) via LDS tile transpose, both sides coalesced.
// Bt2[mat][chunk 0..15][gcol][j 0..31] = bf16hi(U[chunk*32+j][gcol]). grid (24,16,3).
__global__ __launch_bounds__(256) void precomp_Bt2(
    const float* __restrict__ Uf, const float* __restrict__ Ub, const float* __restrict__ Ud,
    ushort_t* __restrict__ BtF, ushort_t* __restrict__ BtB, ushort_t* __restrict__ BtD) {
    const int mat = blockIdx.z;
    const float* U = (mat == 0) ? Uf : (mat == 1) ? Ub : Ud;
    ushort_t* Bt   = (mat == 0) ? BtF : (mat == 1) ? BtB : BtD;
    const int c  = blockIdx.y;          // chunk
    const int ct = blockIdx.x * 64;     // gcol tile
    const int kb = c * 32;

    __shared__ float tile[32][65];
    const int gc = threadIdx.x & 63;
    const int j0 = threadIdx.x >> 6;    // 0..3
#pragma unroll
    for (int s = 0; s < 8; ++s) {
        const int j = j0 * 8 + s;
        tile[j][gc] = U[(size_t)(kb + j) * GN + ct + gc];
    }
    __syncthreads();
    const int j  = threadIdx.x & 31;
    const int g0 = threadIdx.x >> 5;    // 0..7
#pragma unroll
    for (int p = 0; p < 8; ++p) {
        const int gcl = p * 8 + g0;
        Bt[((size_t)c * GN + ct + gcl) * 32 + j] = f2bf(tile[j][gcl]);
    }
}

// Logits B (3-term) via LDS tile transpose: Wot2[chunk 0..31][col][j]; 0..15 hi, 16..31 lo.
__global__ __launch_bounds__(256) void precomp_Wot2(
    const float* __restrict__ Wo, ushort_t* __restrict__ Wot) {
    const int c  = blockIdx.y;          // 0..31
    const int ct = blockIdx.x * 64;
    const int kb = (c < 16) ? c * 32 : (c - 16) * 32;

    __shared__ float tile[32][65];
    const int gc = threadIdx.x & 63;
    const int j0 = threadIdx.x >> 6;
#pragma unroll
    for (int s = 0; s < 8; ++s) {
        const int j = j0 * 8 + s;
        tile[j][gc] = Wo[(size_t)(kb + j) * VN + ct + gc];
    }
    __syncthreads();
    const int j  = threadIdx.x & 31;
    const int g0 = threadIdx.x >> 5;
#pragma unroll
    for (int p = 0; p < 8; ++p) {
        const int gcl = p * 8 + g0;
        float u = tile[j][gcl];
        ushort_t hi = f2bf(u);
        Wot[((size_t)c * VN + ct + gcl) * 32 + j] = (c >= 16) ? f2bf(u - bf2f(hi)) : hi;
    }
}

__global__ void dec_init(const ushort_t* __restrict__ hf, const ushort_t* __restrict__ hb,
                         ushort_t* __restrict__ hd) {
    int i = blockIdx.x * blockDim.x + threadIdx.x;
    if (i >= BN_ * HN) return;
    int row = i >> 9, col = i & (HN - 1);
    float h = bf2f(hf[(size_t)row * HC + col]) + bf2f(hf[(size_t)row * HC + HN + col])
            + bf2f(hb[(size_t)row * HC + col]) + bf2f(hb[(size_t)row * HC + HN + col]);
    ushort_t hi = f2bf(h);
    hd[(size_t)row * HC + col] = hi;
    hd[(size_t)row * HC + HN + col] = f2bf(h - bf2f(hi));
}

// ===== Encoder step: both dirs, MT=64, 4 waves of 64x16x3gates. Grid (128,8). =====
// XCD = bx%8 (128*by == 0 mod 8): dir = bx&4 (fwd XCD 0-3, bwd 4-7),
// rtile = (bx>>3)*4 + (bx&3) in 0..63. 1024 blocks = 4/CU (LDS 40KB, 160 exact).
// 16 chunks; per chunk stage {A-hi 4K, A-lo 4K, B 12K} (B once). vmcnt(5) = 1 stage.
// t==0 fast path: h_in == 0 -> skip all staging/MFMA (acc=0, ho=0).
__global__ __launch_bounds__(256, 4) void enc_step(
    const ushort_t* __restrict__ hf_in, ushort_t* __restrict__ hf_out,
    const ushort_t* __restrict__ BtF, const float* __restrict__ brF, const float* __restrict__ Pf,
    const ushort_t* __restrict__ hb_in, ushort_t* __restrict__ hb_out,
    const ushort_t* __restrict__ BtB, const float* __restrict__ brB, const float* __restrict__ Pb,
    const int* __restrict__ src, int t) {
    const int bx = blockIdx.x;
    const ushort_t* hin; ushort_t* hout; const ushort_t* Bt; const float* brec; const float* P; int rev;
    if ((bx & 4) == 0) { hin = hf_in; hout = hf_out; Bt = BtF; brec = brF; P = Pf; rev = 0; }
    else               { hin = hb_in; hout = hb_out; Bt = BtB; brec = brB; P = Pb; rev = 1; }
    const int bm = ((bx >> 3) * 4 + (bx & 3)) * 64;
    const int bj = blockIdx.y * 64;
    const int tid = threadIdx.x;
    const int lane = tid & 63;
    const int w = tid >> 6;
    const int fl = lane & 15;
    const int fke = (((lane >> 4) ^ ((lane >> 1) & 3)) * 8);    // swizzled read slot
    const int lr = lane >> 2;
    const int lk = (((lane & 3) ^ ((lane >> 3) & 3)) * 8);      // swizzled global slot
    const int fq = lane >> 4;

    __shared__ __align__(16) short SM[2][320 * 32];   // A-hi 0..63, A-lo 64..127, B 128..319

    f32x4 acc[3][4];
#pragma unroll
    for (int g = 0; g < 3; g++)
#pragma unroll
        for (int i = 0; i < 4; i++) acc[g][i] = (f32x4){0.f, 0.f, 0.f, 0.f};

    auto stage = [&](int buf, int kc) {
        const int ah = kc * 32;
        const int al = 512 + kc * 32;
        const int r0a = w * 16;
        gload16(hin + (size_t)(bm + r0a + lr) * HC + ah + lk, &SM[buf][r0a * 32]);
        gload16(hin + (size_t)(bm + r0a + lr) * HC + al + lk, &SM[buf][(64 + r0a) * 32]);
#pragma unroll
        for (int s = 0; s < 3; ++s) {
            const int r0 = w * 48 + s * 16;
            const int r = r0 + lr;
            const int gcol = ((r >> 6) << 9) + bj + (r & 63);
            gload16(Bt + ((size_t)kc * GN + gcol) * 32 + lk, &SM[buf][(128 + r0) * 32]);
        }
    };
    auto compute = [&](int cur) {
        const short* Ab = &SM[cur][0];
        const short* Bb = &SM[cur][128 * 32];
        bf16x8 ah[4], al[4];
#pragma unroll
        for (int i = 0; i < 4; i++) {
            ah[i] = *(const bf16x8*)&Ab[(i * 16 + fl) * 32 + fke];
            al[i] = *(const bf16x8*)&Ab[(64 + i * 16 + fl) * 32 + fke];
        }
#pragma unroll
        for (int g = 0; g < 3; g++) {
            bf16x8 bfr = *(const bf16x8*)&Bb[(g * 64 + w * 16 + fl) * 32 + fke];
#pragma unroll
            for (int i = 0; i < 4; i++) {
                acc[g][i] = __builtin_amdgcn_mfma_f32_16x16x32_bf16(ah[i], bfr, acc[g][i], 0, 0, 0);
                acc[g][i] = __builtin_amdgcn_mfma_f32_16x16x32_bf16(al[i], bfr, acc[g][i], 0, 0, 0);
            }
        }
    };

    if (t > 0) {   // t==0: h_in == 0 -> GEMM result is 0; skip staging entirely
        stage(0, 0);
        for (int kc = 0; kc < 16; ++kc) {
            if (kc < 15) { stage((kc + 1) & 1, kc + 1); waitcnt_vm<5>(); }
            else         { waitcnt_vm<0>(); }
            barrier_();
            compute(kc & 1);
            barrier_();
        }
    }

#pragma unroll
    for (int i = 0; i < 4; i++) {
#pragma unroll
        for (int q = 0; q < 4; q++) {
            const int row = bm + i * 16 + fq * 4 + q;
            const int idx = src[row * SN + (rev ? (SN - 1 - t) : t)];
            const float* Pr = P + (size_t)idx * GN;
            const int col = bj + w * 16 + fl;
            float rz = acc[0][i][q] + brec[col];
            float rr = acc[1][i][q] + brec[HN + col];
            float rh = acc[2][i][q] + brec[2 * HN + col];
            float z = 1.f / (1.f + expf(-(Pr[col] + rz)));
            float r = 1.f / (1.f + expf(-(Pr[HN + col] + rr)));
            float hh = tanhf(Pr[2 * HN + col] + r * rh);
            float ho = (t > 0) ? (bf2f(hin[(size_t)row * HC + col]) + bf2f(hin[(size_t)row * HC + HN + col]))
                               : 0.f;
            float hnew = z * ho + (1.f - z) * hh;
            ushort_t hib = f2bf(hnew);
            hout[(size_t)row * HC + col] = hib;
            hout[(size_t)row * HC + HN + col] = f2bf(hnew - bf2f(hib));
        }
    }
}

// ===== Fused decoder step t (16 chunks, B-once) + logits of t-1 (48 chunks, 3-term). =====
// dec buffer: A-hi rows 0..63, A-lo 64..127, B 128..319 -> 20KB/buf; LDS 40KB, 3 blocks/CU.
__global__ __launch_bounds__(256, 3) void dec_fused(
    const ushort_t* __restrict__ hin, ushort_t* __restrict__ hout,
    const ushort_t* __restrict__ BtD, const float* __restrict__ brD, const float* __restrict__ Pd,
    const int* __restrict__ tgt, const ushort_t* __restrict__ Wot,
    const float* __restrict__ bo, float* __restrict__ out, int t) {
    const int bx = blockIdx.x;
    const int tid = threadIdx.x;
    const int lane = tid & 63;
    const int w = tid >> 6;
    const int fl = lane & 15;
    const int fke = (((lane >> 4) ^ ((lane >> 1) & 3)) * 8);
    const int lr = lane >> 2;
    const int lk = (((lane & 3) ^ ((lane >> 3) & 3)) * 8);
    const int fq = lane >> 4;

    __shared__ __align__(16) short SM[2][320 * 32];

    if (bx < 512) {
        const int bm = (bx & 63) * 64;
        const int bj = (bx >> 6) * 64;

        f32x4 acc[3][4];
#pragma unroll
        for (int g = 0; g < 3; g++)
#pragma unroll
            for (int i = 0; i < 4; i++) acc[g][i] = (f32x4){0.f, 0.f, 0.f, 0.f};

        auto stage = [&](int buf, int kc) {
            const int ah = kc * 32;
            const int al = 512 + kc * 32;
            const int r0a = w * 16;
            gload16(hin + (size_t)(bm + r0a + lr) * HC + ah + lk, &SM[buf][r0a * 32]);
            gload16(hin + (size_t)(bm + r0a + lr) * HC + al + lk, &SM[buf][(64 + r0a) * 32]);
#pragma unroll
            for (int s = 0; s < 3; ++s) {
                const int r0 = w * 48 + s * 16;
                const int r = r0 + lr;
                const int gcol = ((r >> 6) << 9) + bj + (r & 63);
                gload16(BtD + ((size_t)kc * GN + gcol) * 32 + lk, &SM[buf][(128 + r0) * 32]);
            }
        };
        auto compute = [&](int cur) {
            const short* Ab = &SM[cur][0];
            const short* Bb = &SM[cur][128 * 32];
            bf16x8 ah[4], al[4];
#pragma unroll
            for (int i = 0; i < 4; i++) {
                ah[i] = *(const bf16x8*)&Ab[(i * 16 + fl) * 32 + fke];
                al[i] = *(const bf16x8*)&Ab[(64 + i * 16 + fl) * 32 + fke];
            }
#pragma unroll
            for (int g = 0; g < 3; g++) {
                bf16x8 bfr = *(const bf16x8*)&Bb[(g * 64 + w * 16 + fl) * 32 + fke];
#pragma unroll
                for (int i = 0; i < 4; i++) {
                    acc[g][i] = __builtin_amdgcn_mfma_f32_16x16x32_bf16(ah[i], bfr, acc[g][i], 0, 0, 0);
                    acc[g][i] = __builtin_amdgcn_mfma_f32_16x16x32_bf16(al[i], bfr, acc[g][i], 0, 0, 0);
                }
            }
        };

        stage(0, 0);
        for (int kc = 0; kc < 16; ++kc) {
            if (kc < 15) { stage((kc + 1) & 1, kc + 1); waitcnt_vm<5>(); }
            else         { waitcnt_vm<0>(); }
            barrier_();
            compute(kc & 1);
            barrier_();
        }

#pragma unroll
        for (int i = 0; i < 4; i++) {
#pragma unroll
            for (int q = 0; q < 4; q++) {
                const int row = bm + i * 16 + fq * 4 + q;
                const int idx = (t == 0) ? BOW_ : tgt[row * TN + (t - 1)];
                const float* Pr = Pd + (size_t)idx * GN;
                const int col = bj + w * 16 + fl;
                float rz = acc[0][i][q] + brD[col];
                float rr = acc[1][i][q] + brD[HN + col];
                float rh = acc[2][i][q] + brD[2 * HN + col];
                float z = 1.f / (1.f + expf(-(Pr[col] + rz)));
                float r = 1.f / (1.f + expf(-(Pr[HN + col] + rr)));
                float hh = tanhf(Pr[2 * HN + col] + r * rh);
                float ho = bf2f(hin[(size_t)row * HC + col]) + bf2f(hin[(size_t)row * HC + HN + col]);
                float hnew = z * ho + (1.f - z) * hh;
                ushort_t hib = f2bf(hnew);
                hout[(size_t)row * HC + col] = hib;
                hout[(size_t)row * HC + HN + col] = f2bf(hnew - bf2f(hib));
            }
        }
    } else {
        if (t == 0) return;
        const int l = bx - 512;
        const int bm = (l & 63) * 64;
        const int bn = (l >> 6) * 64;

        f32x4 acc[4];
#pragma unroll
        for (int i = 0; i < 4; i++) acc[i] = (f32x4){0.f, 0.f, 0.f, 0.f};

        // 48 chunks: 0..15 Ahi x Wohi, 16..31 Alo x Wohi, 32..47 Ahi x Wolo
        auto stage = [&](int buf, int kc) {
            const int aS = (kc < 16) ? (kc * 32) : (kc < 32) ? (512 + (kc - 16) * 32) : ((kc - 32) * 32);
            const int wfix = (kc < 32) ? (kc & 15) : (16 + (kc - 32));
            const int r0 = w * 16;
            gload16(hin + (size_t)(bm + r0 + lr) * HC + aS + lk, &SM[buf][r0 * 32]);
            gload16(Wot + ((size_t)wfix * VN + bn + r0 + lr) * 32 + lk, &SM[buf][(64 + r0) * 32]);
        };
        auto compute = [&](int cur) {
            const short* Ab = &SM[cur][0];
            const short* Bb = &SM[cur][64 * 32];
            bf16x8 bfr = *(const bf16x8*)&Bb[(w * 16 + fl) * 32 + fke];
#pragma unroll
            for (int i = 0; i < 4; i++) {
                bf16x8 af = *(const bf16x8*)&Ab[(i * 16 + fl) * 32 + fke];
                acc[i] = __builtin_amdgcn_mfma_f32_16x16x32_bf16(af, bfr, acc[i], 0, 0, 0);
            }
        };

        stage(0, 0);
        for (int kc = 0; kc < 48; ++kc) {
            if (kc < 47) { stage((kc + 1) & 1, kc + 1); waitcnt_vm<2>(); }
            else         { waitcnt_vm<0>(); }
            barrier_();
            compute(kc & 1);
            barrier_();
        }

#pragma unroll
        for (int i = 0; i < 4; i++) {
#pragma unroll
            for (int q = 0; q < 4; q++) {
                const int row = bm + i * 16 + fq * 4 + q;
                const int col = bn + w * 16 + fl;
                out[(size_t)row * (TN * VN) + (t - 1) * VN + col] = acc[i][q] + bo[col];
            }
        }
    }
}

// standalone logits for the final decoder output (t = TN-1), 3-term, 48 chunks
__global__ __launch_bounds__(256) void logits_mfma(
    const ushort_t* __restrict__ hin, const ushort_t* __restrict__ Wot,
    const float* __restrict__ bo, float* __restrict__ out, int t) {
    const int bm = blockIdx.x * 64;
    const int bn = blockIdx.y * 64;
    const int tid = threadIdx.x;
    const int lane = tid & 63;
    const int w = tid >> 6;

    __shared__ __align__(16) short Asm[2][64 * 32];
    __shared__ __align__(16) short Bsm[2][64 * 32];

    f32x4 acc[4];
#pragma unroll
    for (int i = 0; i < 4; i++) acc[i] = (f32x4){0.f, 0.f, 0.f, 0.f};

    const int fl = lane & 15;
    const int fke = (((lane >> 4) ^ ((lane >> 1) & 3)) * 8);
    const int lr = lane >> 2;
    const int lk = (((lane & 3) ^ ((lane >> 3) & 3)) * 8);

    auto stage = [&](int buf, int kc) {
        const int aS = (kc < 16) ? (kc * 32) : (kc < 32) ? (512 + (kc - 16) * 32) : ((kc - 32) * 32);
        const int wfix = (kc < 32) ? (kc & 15) : (16 + (kc - 32));
        const int r0 = w * 16;
        gload16(hin + (size_t)(bm + r0 + lr) * HC + aS + lk, &Asm[buf][r0 * 32]);
        gload16(Wot + ((size_t)wfix * VN + bn + r0 + lr) * 32 + lk, &Bsm[buf][r0 * 32]);
    };
    auto compute = [&](int cur) {
        const short* Ab = Asm[cur];
        const short* Bb = Bsm[cur];
        bf16x8 bfr = *(const bf16x8*)&Bb[(w * 16 + fl) * 32 + fke];
#pragma unroll
        for (int i = 0; i < 4; i++) {
            bf16x8 af = *(const bf16x8*)&Ab[(i * 16 + fl) * 32 + fke];
            acc[i] = __builtin_amdgcn_mfma_f32_16x16x32_bf16(af, bfr, acc[i], 0, 0, 0);
        }
    };

    stage(0, 0);
    for (int kc = 0; kc < 48; ++kc) {
        if (kc < 47) { stage((kc + 1) & 1, kc + 1); waitcnt_vm<2>(); }
        else         { waitcnt_vm<0>(); }
        barrier_();
        compute(kc & 1);
        barrier_();
    }

    const int fq = lane >> 4;
#pragma unroll
    for (int i = 0; i < 4; i++) {
#pragma unroll
        for (int q = 0; q < 4; q++) {
            const int row = bm + i * 16 + fq * 4 + q;
            const int col = bn + w * 16 + fl;
            out[(size_t)row * (TN * VN) + t * VN + col] = acc[i][q] + bo[col];
        }
    }
}

extern "C" void kernel_launch(void* const* d_in, const int* in_sizes, int n_in,
                              void* d_out, int out_size, void* d_ws, size_t ws_size,
                              hipStream_t stream) {
    const int* source    = (const int*)d_in[0];
    const int* targets   = (const int*)d_in[1];
    const float* src_emb = (const float*)d_in[2];
    const float* tgt_emb = (const float*)d_in[3];
    const float* Wf = (const float*)d_in[4];
    const float* Uf = (const float*)d_in[5];
    const float* bf = (const float*)d_in[6];
    const float* Wb = (const float*)d_in[7];
    const float* Ub = (const float*)d_in[8];
    const float* bb = (const float*)d_in[9];
    const float* Wd = (const float*)d_in[10];
    const float* Ud = (const float*)d_in[11];
    const float* bd = (const float*)d_in[12];
    const float* Wo = (const float*)d_in[13];
    const float* bo = (const float*)d_in[14];
    float* out = (float*)d_out;

    char* ws = (char*)d_ws;
    ushort_t* BtF = (ushort_t*)(ws);                    // 16*1536*32*2 = 1572864 each
    ushort_t* BtB = (ushort_t*)(ws + 1572864);
    ushort_t* BtD = (ushort_t*)(ws + 2 * 1572864);
    ushort_t* Wot = (ushort_t*)(ws + 3 * 1572864);      // 32*256*32*2 = 524288
    float*    Pf  = (float*)   (ws + 3 * 1572864 + 524288);  // 3*256*1536*4 = 4718592
    float*    Pb  = Pf + VN * GN;
    float*    Pd  = Pb + VN * GN;
    char* hbase = ws + 3 * 1572864 + 524288 + 4718592;  // 4 x 4096*1024*2 = 4 x 8388608
    ushort_t* hf0 = (ushort_t*)(hbase);
    ushort_t* hf1 = (ushort_t*)(hbase + 8388608);
    ushort_t* hb0 = (ushort_t*)(hbase + 2 * 8388608);
    ushort_t* hb1 = (ushort_t*)(hbase + 3 * 8388608);

    precomp_P<<<dim3(4, 24, 3), 256, 0, stream>>>(src_emb, tgt_emb, Wf, bf, Wb, bb, Wd, bd, Pf, Pb, Pd);
    precomp_Bt2<<<dim3(24, 16, 3), 256, 0, stream>>>(Uf, Ub, Ud, BtF, BtB, BtD);
    precomp_Wot2<<<dim3(4, 32), 256, 0, stream>>>(Wo, Wot);

    // encoder: grid (128,8): XCD 0-3 fwd / 4-7 bwd, 64-row tiles, 4 blocks/CU.
    // t==0 reads no h state (fast path), so hf0/hb0 need no zero-init.
    for (int t = 0; t < SN; t++) {
        const ushort_t* hfi = (t & 1) ? hf1 : hf0; ushort_t* hfo = (t & 1) ? hf0 : hf1;
        const ushort_t* hbi = (t & 1) ? hb1 : hb0; ushort_t* hbo = (t & 1) ? hb0 : hb1;
        enc_step<<<dim3(128, 8), 256, 0, stream>>>(
            hfi, hfo, BtF, bf + GN, Pf,
            hbi, hbo, BtB, bb + GN, Pb,
            source, t);
    }
    dec_init<<<(BN_ * HN + 255) / 256, 256, 0, stream>>>(hf0, hb0, hb1);

    // fused decoder step t + logits(t-1); ping-pong hb1 <-> hf1
    for (int t = 0; t < TN; t++) {
        const ushort_t* hdi = (t & 1) ? hf1 : hb1; ushort_t* hdo = (t & 1) ? hb1 : hf1;
        dec_fused<<<768, 256, 0, stream>>>(
            hdi, hdo, BtD, bd + GN, Pd, targets, Wot, bo, out, t);
    }
    // final logits for t = 23 output (hdo of t=23 is hb1 since 23 is odd)
    logits_mfma<<<dim3(64, 4), 256, 0, stream>>>(hb1, Wot, bo, out, TN - 1);
}